// Round 15
// baseline (323.742 us; speedup 1.0000x reference)
//
#include <hip/hip_runtime.h>
#include <math.h>

#define BB 16
#define CC 256
#define TT 4096
#define NA 1024
#define NB 3072
#define OC 512

#define NCH 12         // j-chunks for MFMA sim kernel (256 j each = 2 tiles of 128)
#define NPART NCH      // partials: one per chunk (wc halves merged in-block via LDS)
#define DELTA 2e-4f    // pair-safe margin: DELTA > 2*err (err<=5e-5, C-S bound)

typedef float f32x4 __attribute__((ext_vector_type(4)));
typedef short bf16x8 __attribute__((ext_vector_type(8)));

// in-place top-3 merge of state (a1,ai1,a2,ai2,a3) with (b1,bi1,b2,bi2,b3)
// values strict-desc; ties -> smaller index (numpy first-occurrence)
#define MERGE5(a1,ai1,a2,ai2,a3, b1,bi1,b2,bi2,b3) {                              \
    bool sw = ((b1) > (a1)) || ((b1) == (a1) && (bi1) < (ai1));                   \
    float A1 = sw ? (b1) : (a1); int Ai1 = sw ? (bi1) : (ai1);                    \
    float A2 = sw ? (b2) : (a2); int Ai2 = sw ? (bi2) : (ai2);                    \
    float A3 = sw ? (b3) : (a3);                                                  \
    float B1 = sw ? (a1) : (b1); int Bi1 = sw ? (ai1) : (bi1);                    \
    float B2 = sw ? (a2) : (b2);                                                  \
    bool t2 = (B1 > A2) || (B1 == A2 && Bi1 < Ai2);                               \
    float n3 = t2 ? fmaxf(A2, B2) : fmaxf(A3, B1);                                \
    a2 = t2 ? B1 : A2; ai2 = t2 ? Bi1 : Ai2;                                      \
    a1 = A1; ai1 = Ai1; a3 = n3;                                                  \
}

// insert value x (index j) into (v1,i1,v2,i2,v3); ascending-j call order
#define INS3(x, j) {                                                              \
    if ((x) > v1) { v3 = v2; v2 = v1; i2 = i1; v1 = (x); i1 = (j); }              \
    else if ((x) > v2) { v3 = v2; v2 = (x); i2 = (j); }                           \
    else v3 = fmaxf(v3, (x));                                                     \
}

// ---------------- K1: per-token L2 norm over C ----------------
__global__ void k_norm(const float* __restrict__ x, float* __restrict__ norms) {
    int idx = blockIdx.x * 256 + threadIdx.x;   // b*TT + t
    int b = idx >> 12;
    int t = idx & 4095;
    const float* xp = x + (size_t)b * CC * TT + t;
    float s = 0.f;
#pragma unroll 8
    for (int c = 0; c < CC; ++c) {
        float v = xp[(size_t)c * TT];
        s = fmaf(v, v, s);
    }
    norms[idx] = sqrtf(s);
}

// ---------------- K2: transpose-pack normalized a/b tokens (fp32 only) ----------------
__global__ void k_pack(const float* __restrict__ x, const float* __restrict__ norms,
                       float* __restrict__ Ap, float* __restrict__ Bp) {
    __shared__ float tile[64][65];
    __shared__ float ns[64];
    int b = blockIdx.z, c0 = blockIdx.y * 64, t0 = blockIdx.x * 64;
    int tid = threadIdx.x;
#pragma unroll
    for (int rep = 0; rep < 16; ++rep) {
        int lin = rep * 256 + tid;
        int i = lin >> 6, j = lin & 63;
        tile[i][j] = x[((size_t)b * CC + c0 + i) * TT + t0 + j];
    }
    if (tid < 64) ns[tid] = norms[b * TT + t0 + tid];
    __syncthreads();
#pragma unroll
    for (int rep = 0; rep < 16; ++rep) {
        int lin = rep * 256 + tid;
        int j = lin >> 6, i = lin & 63;
        int t = t0 + j;
        float v = tile[i][j] / ns[j];
        if ((t & 3) == 0) {
            Ap[((size_t)b * NA + (t >> 2)) * CC + c0 + i] = v;
        } else {
            int g = t >> 2, r = t & 3;
            Bp[((size_t)b * NB + 3 * g + (r - 1)) * CC + c0 + i] = v;
        }
    }
}

// ---------------- K3: MFMA sim; T14 async-STAGE; top-3 epilogue via LDS scratch ----------------
__device__ inline void split8(float4 p0, float4 p1, bf16x8& hi, bf16x8& lo) {
    float f[8] = {p0.x, p0.y, p0.z, p0.w, p1.x, p1.y, p1.z, p1.w};
#pragma unroll
    for (int j = 0; j < 8; ++j) {
        uint u = __float_as_uint(f[j]);
        hi[j] = (short)(u >> 16);
        float hf = __uint_as_float(u & 0xffff0000u);
        lo[j] = (short)(__float_as_uint(f[j] - hf) >> 16);
    }
}

#define LOADT(SRC_BASE, KT, RG)                                                   \
    _Pragma("unroll")                                                             \
    for (int rep = 0; rep < 4; ++rep) {                                           \
        int lin = rep * 256 + tid;                                                \
        int r = lin >> 3, g = lin & 7;                                            \
        const float* sp = (SRC_BASE) + (size_t)r * CC + (KT) * 64 + g * 8;        \
        RG[rep][0] = *(const float4*)sp;                                          \
        RG[rep][1] = *(const float4*)(sp + 4);                                    \
    }

#define WRITET(RG, DH, DL)                                                        \
    _Pragma("unroll")                                                             \
    for (int rep = 0; rep < 4; ++rep) {                                           \
        int lin = rep * 256 + tid;                                                \
        int r = lin >> 3, g = lin & 7;                                            \
        bf16x8 h8, l8;                                                            \
        split8(RG[rep][0], RG[rep][1], h8, l8);                                   \
        int off = r * 128 + ((g ^ (r & 7)) << 4);                                 \
        *(bf16x8*)((DH) + off) = h8;                                              \
        *(bf16x8*)((DL) + off) = l8;                                              \
    }

#define MFMA_TILE(ACC)                                                            \
    _Pragma("unroll")                                                             \
    for (int ks = 0; ks < 2; ++ks) {                                              \
        bf16x8 ahi[4], alo[4];                                                    \
        _Pragma("unroll")                                                         \
        for (int mf = 0; mf < 4; ++mf) {                                          \
            int ra = wr * 64 + mf * 16 + lr;                                      \
            int offa = ra * 128 + (((ks * 4 + lk) ^ (ra & 7)) << 4);              \
            ahi[mf] = *(const bf16x8*)(Ah + offa);                                \
            alo[mf] = *(const bf16x8*)(Al + offa);                                \
        }                                                                         \
        _Pragma("unroll")                                                         \
        for (int nf = 0; nf < 4; ++nf) {                                          \
            int rb = wc * 64 + nf * 16 + lr;                                      \
            int offb = rb * 128 + (((ks * 4 + lk) ^ (rb & 7)) << 4);              \
            bf16x8 bhi = *(const bf16x8*)(Bh + offb);                             \
            bf16x8 blo = *(const bf16x8*)(Bl + offb);                             \
            _Pragma("unroll")                                                     \
            for (int mf = 0; mf < 4; ++mf) {                                      \
                ACC[mf][nf] = __builtin_amdgcn_mfma_f32_16x16x32_bf16(ahi[mf], blo, ACC[mf][nf], 0, 0, 0); \
                ACC[mf][nf] = __builtin_amdgcn_mfma_f32_16x16x32_bf16(alo[mf], bhi, ACC[mf][nf], 0, 0, 0); \
                ACC[mf][nf] = __builtin_amdgcn_mfma_f32_16x16x32_bf16(ahi[mf], bhi, ACC[mf][nf], 0, 0, 0); \
            }                                                                     \
        }                                                                         \
    }

__global__ void __launch_bounds__(256, 2) k_sim(const float* __restrict__ Ap,
                                                const float* __restrict__ Bp,
                                                float* __restrict__ Pv1, int* __restrict__ Pi1,
                                                float* __restrict__ Pv2, int* __restrict__ Pi2,
                                                float* __restrict__ Pv3) {
    __shared__ __align__(16) char lds[65536];   // Ah|Al|Bh|Bl, 16KB each; reused as top3 scratch
    char* Ah = lds;
    char* Al = lds + 16384;
    char* Bh = lds + 32768;
    char* Bl = lds + 49152;
    const int b = blockIdx.z;
    const int ch = blockIdx.y;
    const int i0 = blockIdx.x * 128;
    const int tid = threadIdx.x;
    const int l = tid & 63, wid = tid >> 6;
    const int wr = wid >> 1, wc = wid & 1;      // 2x2 wave grid, 64x64 per wave per tile
    const int lr = l & 15, lk = l >> 4;
    const float* Abase = Ap + ((size_t)b * NA + i0) * CC;
    const float* Bbase = Bp + (size_t)b * NB * CC;
    const int j0c = ch * 256;

    f32x4 acc0[4][4], acc1[4][4];
#pragma unroll
    for (int mf = 0; mf < 4; ++mf)
#pragma unroll
        for (int nf = 0; nf < 4; ++nf) {
            acc0[mf][nf] = (f32x4){0.f, 0.f, 0.f, 0.f};
            acc1[mf][nf] = (f32x4){0.f, 0.f, 0.f, 0.f};
        }

    float4 rA[4][2], rB[4][2];
    LOADT(Abase, 0, rA)
    LOADT(Bbase + (size_t)j0c * CC, 0, rB)

    for (int kt = 0; kt < 4; ++kt) {
        __syncthreads();                      // prior tile reads done
        WRITET(rA, Ah, Al)
        WRITET(rB, Bh, Bl)
        __syncthreads();
        LOADT(Bbase + (size_t)(j0c + 128) * CC, kt, rB)   // issue B2 loads under MFMA0
        MFMA_TILE(acc0)
        __syncthreads();
        WRITET(rB, Bh, Bl)
        __syncthreads();
        if (kt < 3) {
            LOADT(Abase, kt + 1, rA)
            LOADT(Bbase + (size_t)j0c * CC, kt + 1, rB)
        }
        MFMA_TILE(acc1)
    }

    // ---- top-3 epilogue; LDS scratch after all MFMA reads retire ----
    __syncthreads();
    float* fs = (float*)lds;                  // [wc][wr][row64][6] floats (5 used)
#pragma unroll
    for (int mf = 0; mf < 4; ++mf)
#pragma unroll
        for (int reg = 0; reg < 4; ++reg) {
            float v1 = acc0[mf][0][reg];
            int i1 = j0c + wc * 64 + lr;
            float v2 = -1e30f, v3 = -1e30f;
            int i2 = 0x7fffffff;
#pragma unroll
            for (int nf = 1; nf < 4; ++nf) INS3(acc0[mf][nf][reg], j0c + wc * 64 + nf * 16 + lr)
#pragma unroll
            for (int nf = 0; nf < 4; ++nf) INS3(acc1[mf][nf][reg], j0c + 128 + wc * 64 + nf * 16 + lr)
#pragma unroll
            for (int d = 1; d < 16; d <<= 1) {
                float o1 = __shfl_xor(v1, d, 64);
                int oi1 = __shfl_xor(i1, d, 64);
                float o2 = __shfl_xor(v2, d, 64);
                int oi2 = __shfl_xor(i2, d, 64);
                float o3 = __shfl_xor(v3, d, 64);
                MERGE5(v1, i1, v2, i2, v3, o1, oi1, o2, oi2, o3)
            }
            if (lr == 0) {
                int base = ((wc * 128 + wr * 64) + mf * 16 + lk * 4 + reg) * 6;
                fs[base + 0] = v1; fs[base + 1] = __int_as_float(i1);
                fs[base + 2] = v2; fs[base + 3] = __int_as_float(i2);
                fs[base + 4] = v3;
            }
        }
    __syncthreads();
    if (wc == 0 && lr == 0) {
#pragma unroll
        for (int mf = 0; mf < 4; ++mf)
#pragma unroll
            for (int reg = 0; reg < 4; ++reg) {
                int rIdx = mf * 16 + lk * 4 + reg;
                int b0 = (wr * 64 + rIdx) * 6;
                int b1 = ((128 + wr * 64) + rIdx) * 6;
                float v1 = fs[b0], v2 = fs[b0 + 2], v3 = fs[b0 + 4];
                int i1 = __float_as_int(fs[b0 + 1]), i2 = __float_as_int(fs[b0 + 3]);
                float u1 = fs[b1], u2 = fs[b1 + 2], u3 = fs[b1 + 4];
                int j1 = __float_as_int(fs[b1 + 1]), j2 = __float_as_int(fs[b1 + 3]);
                MERGE5(v1, i1, v2, i2, v3, u1, j1, u2, j2, u3)
                size_t o = ((size_t)b * NPART + ch) * NA + i0 + wr * 64 + rIdx;
                Pv1[o] = v1; Pi1[o] = i1; Pv2[o] = v2; Pi2[o] = i2; Pv3[o] = v3;
            }
    }
}

// ---------------- K3z: reset worklist count ----------------
__global__ void k_zero(int* __restrict__ count) {
    if (threadIdx.x == 0 && blockIdx.x == 0) *count = 0;
}

// ---------------- K3b: merge partials; classify {safe | pair-rerank | full-fallback} ----------------
__global__ void k_reduce2(const float* __restrict__ Pv1, const int* __restrict__ Pi1,
                          const float* __restrict__ Pv2, const int* __restrict__ Pi2,
                          const float* __restrict__ Pv3,
                          const float* __restrict__ Ap, const float* __restrict__ Bp,
                          int* __restrict__ sel, int* __restrict__ wl, int* __restrict__ count) {
    int idx = blockIdx.x * 256 + threadIdx.x;   // b*NA + a
    int b = idx >> 10;
    int a = idx & 1023;
    float v1 = -1e30f, v2 = -1e30f, v3 = -1e30f;
    int i1 = 0x7fffffff, i2 = 0x7fffffff;
#pragma unroll
    for (int pc = 0; pc < NPART; ++pc) {
        size_t o = ((size_t)b * NPART + pc) * NA + a;
        float u1 = Pv1[o], u2 = Pv2[o], u3 = Pv3[o];
        int j1 = Pi1[o], j2 = Pi2[o];
        MERGE5(v1, i1, v2, i2, v3, u1, j1, u2, j2, u3)
    }
    int pick = i1;
    if (v1 - v2 < DELTA) {
        if (v1 - v3 >= DELTA) {
            // true argmax provably in {i1, i2}: exact fp32 pair re-rank
            const float* ar = Ap + ((size_t)b * NA + a) * CC;
            const float* b1r = Bp + ((size_t)b * NB + i1) * CC;
            const float* b2r = Bp + ((size_t)b * NB + i2) * CC;
            float e1 = 0.f, e2 = 0.f;
            for (int c = 0; c < CC; c += 4) {
                float4 a4 = *(const float4*)(ar + c);
                float4 x4 = *(const float4*)(b1r + c);
                float4 y4 = *(const float4*)(b2r + c);
                e1 = fmaf(a4.w, x4.w, fmaf(a4.z, x4.z, fmaf(a4.y, x4.y, fmaf(a4.x, x4.x, e1))));
                e2 = fmaf(a4.w, y4.w, fmaf(a4.z, y4.z, fmaf(a4.y, y4.y, fmaf(a4.x, y4.x, e2))));
            }
            if (e2 > e1 || (e2 == e1 && i2 < i1)) pick = i2;
        } else {
            int p = atomicAdd(count, 1);
            wl[p] = idx;
        }
    }
    int g = pick / 3, r = pick - 3 * g;
    sel[idx] = 4 * g + r + 1;
}

// ---------------- K3c: exact fp32 re-argmax, full scan (rare rows) ----------------
__global__ void __launch_bounds__(512) k_fallback(const float* __restrict__ Ap,
                                                  const float* __restrict__ Bp,
                                                  const int* __restrict__ wl,
                                                  const int* __restrict__ count,
                                                  int* __restrict__ sel) {
    int n = *count;
    __shared__ float arow[CC];
    __shared__ float wv[8];
    __shared__ int wi[8];
    int tid = threadIdx.x;                // 512 threads = 8 waves
    int l = tid & 63, w = tid >> 6;
    int lg = l & 15, grp = l >> 4;
    for (int it = blockIdx.x; it < n; it += gridDim.x) {
        int row = wl[it];
        int b = row >> 10, a = row & 1023;
        __syncthreads();
        if (tid < 64) *(float4*)&arow[tid * 4] = *(const float4*)(Ap + ((size_t)b * NA + a) * CC + tid * 4);
        __syncthreads();
        float4 av[4];
#pragma unroll
        for (int q = 0; q < 4; ++q) av[q] = *(const float4*)&arow[q * 64 + lg * 4];
        const float* Bb = Bp + (size_t)b * NB * CC;
        float bv = -1e30f;
        int bi = 0;
        for (int j = w * 4 + grp; j < NB; j += 32) {
            const float* br = Bb + (size_t)j * CC + lg * 4;
            float s = 0.f;
#pragma unroll
            for (int q = 0; q < 4; ++q) {
                float4 bb = *(const float4*)(br + q * 64);
                s = fmaf(av[q].w, bb.w, fmaf(av[q].z, bb.z, fmaf(av[q].y, bb.y, fmaf(av[q].x, bb.x, s))));
            }
#pragma unroll
            for (int d = 1; d < 16; d <<= 1) s += __shfl_xor(s, d, 64);
            if (lg == 0 && s > bv) { bv = s; bi = j; }
        }
#pragma unroll
        for (int d = 16; d < 64; d <<= 1) {
            float ov = __shfl_xor(bv, d, 64);
            int oi = __shfl_xor(bi, d, 64);
            if (ov > bv || (ov == bv && oi < bi)) { bv = ov; bi = oi; }
        }
        if (l == 0) { wv[w] = bv; wi[w] = bi; }
        __syncthreads();
        if (tid == 0) {
            float vm = wv[0]; int im = wi[0];
#pragma unroll
            for (int q = 1; q < 8; ++q)
                if (wv[q] > vm || (wv[q] == vm && wi[q] < im)) { vm = wv[q]; im = wi[q]; }
            int g = im / 3, r = im - 3 * g;
            sel[row] = 4 * g + r + 1;
        }
    }
}

// ---------------- K4a: fuse; one block per (b,c), x-row staged in LDS ----------------
__global__ void k_fuse(const float* __restrict__ x, const int* __restrict__ sel,
                       const float* __restrict__ fwraw, float* __restrict__ F) {
    __shared__ float row[TT];
    int b = blockIdx.y, c = blockIdx.x;
    int tid = threadIdx.x;
    const float* xr = x + ((size_t)b * CC + c) * TT;
#pragma unroll
    for (int r = 0; r < 4; ++r)
        *(float4*)&row[r * 1024 + tid * 4] = *(const float4*)(xr + r * 1024 + tid * 4);
    float w0 = fminf(fmaxf(fwraw[0], 0.f), 6.f);
    float w1 = fminf(fmaxf(fwraw[1], 0.f), 6.f);
    float s = w0 + w1 + 1e-8f;
    float fw0 = w0 / s, fw1 = w1 / s;
    __syncthreads();
    float4 outv;
    float* op = &outv.x;
#pragma unroll
    for (int u = 0; u < 4; ++u) {
        int p = tid * 4 + u;
        int lin = 4 * p;
        int spa = ((lin & 63) == 0) ? lin + 1 : lin - 1;
        int ssim = sel[b * NA + p];
        float xa = row[lin], xs = row[ssim], xp = row[spa];
        float ms = (xa + xs) * 0.5f;
        float mp = (xa + xp) * 0.5f;
        op[u] = fw0 * ms + fw1 * mp;
    }
    *(float4*)(F + ((size_t)b * CC + c) * NA + tid * 4) = outv;
}

// ---------------- K4b: 1x1 conv GEMM + BN + SiLU ----------------
__global__ void __launch_bounds__(256) k_conv(const float* __restrict__ F, const float* __restrict__ W,
                                              const float* __restrict__ gamma, const float* __restrict__ beta,
                                              const float* __restrict__ mean, const float* __restrict__ var,
                                              float* __restrict__ out) {
    __shared__ float Ws[16][68];
    __shared__ float Fs[16][68];
    int b = blockIdx.z;
    int o0 = blockIdx.y * 64;
    int p0 = blockIdx.x * 64;
    int tid = threadIdx.x;
    int tr = tid >> 4, tc = tid & 15;
    int sr = tid >> 2, skb = (tid & 3) * 4;
    int fkk = tid >> 4, fj = (tid & 15) * 4;
    const float* Fb = F + (size_t)b * CC * NA;
    float acc[4][4];
#pragma unroll
    for (int u = 0; u < 4; ++u)
#pragma unroll
        for (int v = 0; v < 4; ++v) acc[u][v] = 0.f;

    for (int kt = 0; kt < CC / 16; ++kt) {
        __syncthreads();
        float4 w4 = *(const float4*)(W + (size_t)(o0 + sr) * CC + kt * 16 + skb);
        Ws[skb + 0][sr] = w4.x; Ws[skb + 1][sr] = w4.y;
        Ws[skb + 2][sr] = w4.z; Ws[skb + 3][sr] = w4.w;
        float4 f4 = *(const float4*)(Fb + (size_t)(kt * 16 + fkk) * NA + p0 + fj);
        *(float4*)&Fs[fkk][fj] = f4;
        __syncthreads();
#pragma unroll
        for (int kk = 0; kk < 16; ++kk) {
            float4 av = *(const float4*)&Ws[kk][tr * 4];
            float4 bv4 = *(const float4*)&Fs[kk][tc * 4];
            float a_[4] = {av.x, av.y, av.z, av.w};
            float b_[4] = {bv4.x, bv4.y, bv4.z, bv4.w};
#pragma unroll
            for (int u = 0; u < 4; ++u)
#pragma unroll
                for (int v = 0; v < 4; ++v)
                    acc[u][v] = fmaf(a_[u], b_[v], acc[u][v]);
        }
    }
#pragma unroll
    for (int u = 0; u < 4; ++u) {
        int o = o0 + tr * 4 + u;
        float sc = gamma[o] / sqrtf(var[o] + 1e-5f);
        float sh = fmaf(-mean[o], sc, beta[o]);
        float4 r;
        float* rp = &r.x;
#pragma unroll
        for (int v = 0; v < 4; ++v) {
            float y = fmaf(acc[u][v], sc, sh);
            rp[v] = y / (1.f + expf(-y));
        }
        *(float4*)(out + ((size_t)b * OC + o) * NA + p0 + tc * 4) = r;
    }
}

extern "C" void kernel_launch(void* const* d_in, const int* in_sizes, int n_in,
                              void* d_out, int out_size, void* d_ws, size_t ws_size,
                              hipStream_t stream) {
    const float* x      = (const float*)d_in[0];
    const float* conv_w = (const float*)d_in[1];
    const float* gamma  = (const float*)d_in[2];
    const float* beta   = (const float*)d_in[3];
    const float* mean   = (const float*)d_in[4];
    const float* var    = (const float*)d_in[5];
    const float* fw     = (const float*)d_in[6];
    float* out = (float*)d_out;

    float* ws    = (float*)d_ws;
    float* norms = ws;                                     // BB*TT f
    float* Ap    = norms + (size_t)BB * TT;                // BB*NA*CC f
    float* Bp    = Ap + (size_t)BB * NA * CC;              // BB*NB*CC f
    float* Pv1   = Bp + (size_t)BB * NB * CC;              // BB*NPART*NA f
    float* Pv2   = Pv1 + (size_t)BB * NPART * NA;          // BB*NPART*NA f
    float* Pv3   = Pv2 + (size_t)BB * NPART * NA;          // BB*NPART*NA f
    int*   Pi1   = (int*)(Pv3 + (size_t)BB * NPART * NA);  // BB*NPART*NA i
    int*   Pi2   = Pi1 + (size_t)BB * NPART * NA;          // BB*NPART*NA i
    int*   sel   = Pi2 + (size_t)BB * NPART * NA;          // BB*NA i
    int*   wl    = sel + (size_t)BB * NA;                  // BB*NA i
    int*   count = wl + (size_t)BB * NA;                   // 1 i
    float* F     = Ap;                                     // reuse Ap region after fallback

    k_norm<<<BB * TT / 256, 256, 0, stream>>>(x, norms);
    k_pack<<<dim3(TT / 64, CC / 64, BB), 256, 0, stream>>>(x, norms, Ap, Bp);
    k_sim<<<dim3(NA / 128, NCH, BB), 256, 0, stream>>>(Ap, Bp, Pv1, Pi1, Pv2, Pi2, Pv3);
    k_zero<<<1, 1, 0, stream>>>(count);
    k_reduce2<<<BB * NA / 256, 256, 0, stream>>>(Pv1, Pi1, Pv2, Pi2, Pv3, Ap, Bp, sel, wl, count);
    k_fallback<<<2048, 512, 0, stream>>>(Ap, Bp, wl, count, sel);
    k_fuse<<<dim3(CC, BB), 256, 0, stream>>>(x, sel, fw, F);
    k_conv<<<dim3(NA / 64, OC / 64, BB), 256, 0, stream>>>(F, conv_w, gamma, beta, mean, var, out);
}

// Round 16
// 321.841 us; speedup vs baseline: 1.0059x; 1.0059x over previous
//
#include <hip/hip_runtime.h>
#include <math.h>

#define BB 16
#define CC 256
#define TT 4096
#define NA 1024
#define NB 3072
#define OC 512

#define NCH 12         // j-chunks for MFMA sim kernel (256 j each = 2 tiles of 128)
#define NPART (NCH*2)  // partials: chunk x wc-half (race-free direct per-wave writes)
#define DELTA 2e-4f    // pair-safe margin: DELTA >= 2*err (err<=~9e-5 rigorous)

typedef float f32x4 __attribute__((ext_vector_type(4)));
typedef short bf16x8 __attribute__((ext_vector_type(8)));

// in-place top-3 merge of (a1,ai1,a2,ai2,a3) with (b1,bi1,b2,bi2,b3)
// values strict-desc; ties -> smaller index (numpy first-occurrence). HW-verified R15.
#define MERGE5(a1,ai1,a2,ai2,a3, b1,bi1,b2,bi2,b3) {                              \
    bool sw = ((b1) > (a1)) || ((b1) == (a1) && (bi1) < (ai1));                   \
    float A1 = sw ? (b1) : (a1); int Ai1 = sw ? (bi1) : (ai1);                    \
    float A2 = sw ? (b2) : (a2); int Ai2 = sw ? (bi2) : (ai2);                    \
    float A3 = sw ? (b3) : (a3);                                                  \
    float B1 = sw ? (a1) : (b1); int Bi1 = sw ? (ai1) : (bi1);                    \
    float B2 = sw ? (a2) : (b2);                                                  \
    bool t2 = (B1 > A2) || (B1 == A2 && Bi1 < Ai2);                               \
    float n3 = t2 ? fmaxf(A2, B2) : fmaxf(A3, B1);                                \
    a2 = t2 ? B1 : A2; ai2 = t2 ? Bi1 : Ai2;                                      \
    a1 = A1; ai1 = Ai1; a3 = n3;                                                  \
}

// insert value x (index j) into (v1,i1,v2,i2,v3); ascending-j call order
#define INS3(x, j) {                                                              \
    if ((x) > v1) { v3 = v2; v2 = v1; i2 = i1; v1 = (x); i1 = (j); }              \
    else if ((x) > v2) { v3 = v2; v2 = (x); i2 = (j); }                           \
    else v3 = fmaxf(v3, (x));                                                     \
}

// ---------------- K1: per-token L2 norm over C ----------------
__global__ void k_norm(const float* __restrict__ x, float* __restrict__ norms) {
    int idx = blockIdx.x * 256 + threadIdx.x;   // b*TT + t
    int b = idx >> 12;
    int t = idx & 4095;
    const float* xp = x + (size_t)b * CC * TT + t;
    float s = 0.f;
#pragma unroll 8
    for (int c = 0; c < CC; ++c) {
        float v = xp[(size_t)c * TT];
        s = fmaf(v, v, s);
    }
    norms[idx] = sqrtf(s);
}

// ---------------- K2: transpose-pack normalized a/b tokens (fp32 only) ----------------
__global__ void k_pack(const float* __restrict__ x, const float* __restrict__ norms,
                       float* __restrict__ Ap, float* __restrict__ Bp) {
    __shared__ float tile[64][65];
    __shared__ float ns[64];
    int b = blockIdx.z, c0 = blockIdx.y * 64, t0 = blockIdx.x * 64;
    int tid = threadIdx.x;
#pragma unroll
    for (int rep = 0; rep < 16; ++rep) {
        int lin = rep * 256 + tid;
        int i = lin >> 6, j = lin & 63;
        tile[i][j] = x[((size_t)b * CC + c0 + i) * TT + t0 + j];
    }
    if (tid < 64) ns[tid] = norms[b * TT + t0 + tid];
    __syncthreads();
#pragma unroll
    for (int rep = 0; rep < 16; ++rep) {
        int lin = rep * 256 + tid;
        int j = lin >> 6, i = lin & 63;
        int t = t0 + j;
        float v = tile[i][j] / ns[j];
        if ((t & 3) == 0) {
            Ap[((size_t)b * NA + (t >> 2)) * CC + c0 + i] = v;
        } else {
            int g = t >> 2, r = t & 3;
            Bp[((size_t)b * NB + 3 * g + (r - 1)) * CC + c0 + i] = v;
        }
    }
}

// ---------------- K3: MFMA sim; T14 async-STAGE (R14 pipeline) + top-3 direct epilogue ----------------
__device__ inline void split8(float4 p0, float4 p1, bf16x8& hi, bf16x8& lo) {
    float f[8] = {p0.x, p0.y, p0.z, p0.w, p1.x, p1.y, p1.z, p1.w};
#pragma unroll
    for (int j = 0; j < 8; ++j) {
        uint u = __float_as_uint(f[j]);
        hi[j] = (short)(u >> 16);
        float hf = __uint_as_float(u & 0xffff0000u);
        lo[j] = (short)(__float_as_uint(f[j] - hf) >> 16);
    }
}

#define LOADT(SRC_BASE, KT, RG)                                                   \
    _Pragma("unroll")                                                             \
    for (int rep = 0; rep < 4; ++rep) {                                           \
        int lin = rep * 256 + tid;                                                \
        int r = lin >> 3, g = lin & 7;                                            \
        const float* sp = (SRC_BASE) + (size_t)r * CC + (KT) * 64 + g * 8;        \
        RG[rep][0] = *(const float4*)sp;                                          \
        RG[rep][1] = *(const float4*)(sp + 4);                                    \
    }

#define WRITET(RG, DH, DL)                                                        \
    _Pragma("unroll")                                                             \
    for (int rep = 0; rep < 4; ++rep) {                                           \
        int lin = rep * 256 + tid;                                                \
        int r = lin >> 3, g = lin & 7;                                            \
        bf16x8 h8, l8;                                                            \
        split8(RG[rep][0], RG[rep][1], h8, l8);                                   \
        int off = r * 128 + ((g ^ (r & 7)) << 4);                                 \
        *(bf16x8*)((DH) + off) = h8;                                              \
        *(bf16x8*)((DL) + off) = l8;                                              \
    }

#define MFMA_TILE(ACC)                                                            \
    _Pragma("unroll")                                                             \
    for (int ks = 0; ks < 2; ++ks) {                                              \
        bf16x8 ahi[4], alo[4];                                                    \
        _Pragma("unroll")                                                         \
        for (int mf = 0; mf < 4; ++mf) {                                          \
            int ra = wr * 64 + mf * 16 + lr;                                      \
            int offa = ra * 128 + (((ks * 4 + lk) ^ (ra & 7)) << 4);              \
            ahi[mf] = *(const bf16x8*)(Ah + offa);                                \
            alo[mf] = *(const bf16x8*)(Al + offa);                                \
        }                                                                         \
        _Pragma("unroll")                                                         \
        for (int nf = 0; nf < 4; ++nf) {                                          \
            int rb = wc * 64 + nf * 16 + lr;                                      \
            int offb = rb * 128 + (((ks * 4 + lk) ^ (rb & 7)) << 4);              \
            bf16x8 bhi = *(const bf16x8*)(Bh + offb);                             \
            bf16x8 blo = *(const bf16x8*)(Bl + offb);                             \
            _Pragma("unroll")                                                     \
            for (int mf = 0; mf < 4; ++mf) {                                      \
                ACC[mf][nf] = __builtin_amdgcn_mfma_f32_16x16x32_bf16(ahi[mf], blo, ACC[mf][nf], 0, 0, 0); \
                ACC[mf][nf] = __builtin_amdgcn_mfma_f32_16x16x32_bf16(alo[mf], bhi, ACC[mf][nf], 0, 0, 0); \
                ACC[mf][nf] = __builtin_amdgcn_mfma_f32_16x16x32_bf16(ahi[mf], bhi, ACC[mf][nf], 0, 0, 0); \
            }                                                                     \
        }                                                                         \
    }

__global__ void __launch_bounds__(256, 2) k_sim(const float* __restrict__ Ap,
                                                const float* __restrict__ Bp,
                                                float* __restrict__ Pv1, int* __restrict__ Pi1,
                                                float* __restrict__ Pv2, int* __restrict__ Pi2,
                                                float* __restrict__ Pv3) {
    __shared__ __align__(16) char lds[65536];   // Ah|Al|Bh|Bl, 16KB each ([128][64] bf16 swizzled)
    char* Ah = lds;
    char* Al = lds + 16384;
    char* Bh = lds + 32768;
    char* Bl = lds + 49152;
    const int b = blockIdx.z;
    const int ch = blockIdx.y;
    const int i0 = blockIdx.x * 128;
    const int tid = threadIdx.x;
    const int l = tid & 63, wid = tid >> 6;
    const int wr = wid >> 1, wc = wid & 1;      // 2x2 wave grid, 64x64 per wave per tile
    const int lr = l & 15, lk = l >> 4;
    const float* Abase = Ap + ((size_t)b * NA + i0) * CC;
    const float* Bbase = Bp + (size_t)b * NB * CC;
    const int j0c = ch * 256;

    f32x4 acc0[4][4], acc1[4][4];
#pragma unroll
    for (int mf = 0; mf < 4; ++mf)
#pragma unroll
        for (int nf = 0; nf < 4; ++nf) {
            acc0[mf][nf] = (f32x4){0.f, 0.f, 0.f, 0.f};
            acc1[mf][nf] = (f32x4){0.f, 0.f, 0.f, 0.f};
        }

    float4 rA[4][2], rB[4][2];
    LOADT(Abase, 0, rA)
    LOADT(Bbase + (size_t)j0c * CC, 0, rB)

    for (int kt = 0; kt < 4; ++kt) {
        __syncthreads();                      // prior tile reads done
        WRITET(rA, Ah, Al)
        WRITET(rB, Bh, Bl)
        __syncthreads();
        LOADT(Bbase + (size_t)(j0c + 128) * CC, kt, rB)   // issue B2 loads under MFMA0
        MFMA_TILE(acc0)
        __syncthreads();
        WRITET(rB, Bh, Bl)
        __syncthreads();
        if (kt < 3) {
            LOADT(Abase, kt + 1, rA)
            LOADT(Bbase + (size_t)j0c * CC, kt + 1, rB)
        }
        MFMA_TILE(acc1)
    }

    // ---- top-3(+i2) epilogue: per-row butterfly, direct race-free partial write ----
#pragma unroll
    for (int mf = 0; mf < 4; ++mf)
#pragma unroll
        for (int reg = 0; reg < 4; ++reg) {
            float v1 = acc0[mf][0][reg];
            int i1 = j0c + wc * 64 + lr;
            float v2 = -1e30f, v3 = -1e30f;
            int i2 = 0x7fffffff;
#pragma unroll
            for (int nf = 1; nf < 4; ++nf) INS3(acc0[mf][nf][reg], j0c + wc * 64 + nf * 16 + lr)
#pragma unroll
            for (int nf = 0; nf < 4; ++nf) INS3(acc1[mf][nf][reg], j0c + 128 + wc * 64 + nf * 16 + lr)
#pragma unroll
            for (int d = 1; d < 16; d <<= 1) {
                float o1 = __shfl_xor(v1, d, 64);
                int oi1 = __shfl_xor(i1, d, 64);
                float o2 = __shfl_xor(v2, d, 64);
                int oi2 = __shfl_xor(i2, d, 64);
                float o3 = __shfl_xor(v3, d, 64);
                MERGE5(v1, i1, v2, i2, v3, o1, oi1, o2, oi2, o3)
            }
            if (lr == 0) {
                int pch = ch * 2 + wc;
                size_t o = ((size_t)b * NPART + pch) * NA + i0 + wr * 64 + mf * 16 + lk * 4 + reg;
                Pv1[o] = v1; Pi1[o] = i1; Pv2[o] = v2; Pi2[o] = i2; Pv3[o] = v3;
            }
        }
}

// ---------------- K3z: reset worklist count ----------------
__global__ void k_zero(int* __restrict__ count) {
    if (threadIdx.x == 0 && blockIdx.x == 0) *count = 0;
}

// ---------------- K3b: merge partials; classify {safe | pair-rerank | full-fallback} ----------------
__global__ void k_reduce2(const float* __restrict__ Pv1, const int* __restrict__ Pi1,
                          const float* __restrict__ Pv2, const int* __restrict__ Pi2,
                          const float* __restrict__ Pv3,
                          const float* __restrict__ Ap, const float* __restrict__ Bp,
                          int* __restrict__ sel, int* __restrict__ wl, int* __restrict__ count) {
    int idx = blockIdx.x * 256 + threadIdx.x;   // b*NA + a
    int b = idx >> 10;
    int a = idx & 1023;
    float v1 = -1e30f, v2 = -1e30f, v3 = -1e30f;
    int i1 = 0x7fffffff, i2 = 0x7fffffff;
#pragma unroll
    for (int pc = 0; pc < NPART; ++pc) {
        size_t o = ((size_t)b * NPART + pc) * NA + a;
        float u1 = Pv1[o], u2 = Pv2[o], u3 = Pv3[o];
        int j1 = Pi1[o], j2 = Pi2[o];
        MERGE5(v1, i1, v2, i2, v3, u1, j1, u2, j2, u3)
    }
    int pick = i1;
    if (v1 - v2 < DELTA) {
        if (v1 - v3 >= DELTA) {
            // true argmax provably in {i1, i2}: exact fp32 pair re-rank
            const float* ar = Ap + ((size_t)b * NA + a) * CC;
            const float* b1r = Bp + ((size_t)b * NB + i1) * CC;
            const float* b2r = Bp + ((size_t)b * NB + i2) * CC;
            float e1 = 0.f, e2 = 0.f;
            for (int c = 0; c < CC; c += 4) {
                float4 a4 = *(const float4*)(ar + c);
                float4 x4 = *(const float4*)(b1r + c);
                float4 y4 = *(const float4*)(b2r + c);
                e1 = fmaf(a4.w, x4.w, fmaf(a4.z, x4.z, fmaf(a4.y, x4.y, fmaf(a4.x, x4.x, e1))));
                e2 = fmaf(a4.w, y4.w, fmaf(a4.z, y4.z, fmaf(a4.y, y4.y, fmaf(a4.x, y4.x, e2))));
            }
            if (e2 > e1 || (e2 == e1 && i2 < i1)) pick = i2;
        } else {
            int p = atomicAdd(count, 1);
            wl[p] = idx;
        }
    }
    int g = pick / 3, r = pick - 3 * g;
    sel[idx] = 4 * g + r + 1;
}

// ---------------- K3c: exact fp32 re-argmax, full scan (rare rows) ----------------
__global__ void __launch_bounds__(512) k_fallback(const float* __restrict__ Ap,
                                                  const float* __restrict__ Bp,
                                                  const int* __restrict__ wl,
                                                  const int* __restrict__ count,
                                                  int* __restrict__ sel) {
    int n = *count;
    __shared__ float arow[CC];
    __shared__ float wv[8];
    __shared__ int wi[8];
    int tid = threadIdx.x;                // 512 threads = 8 waves
    int l = tid & 63, w = tid >> 6;
    int lg = l & 15, grp = l >> 4;
    for (int it = blockIdx.x; it < n; it += gridDim.x) {
        int row = wl[it];
        int b = row >> 10, a = row & 1023;
        __syncthreads();
        if (tid < 64) *(float4*)&arow[tid * 4] = *(const float4*)(Ap + ((size_t)b * NA + a) * CC + tid * 4);
        __syncthreads();
        float4 av[4];
#pragma unroll
        for (int q = 0; q < 4; ++q) av[q] = *(const float4*)&arow[q * 64 + lg * 4];
        const float* Bb = Bp + (size_t)b * NB * CC;
        float bv = -1e30f;
        int bi = 0;
        for (int j = w * 4 + grp; j < NB; j += 32) {
            const float* br = Bb + (size_t)j * CC + lg * 4;
            float s = 0.f;
#pragma unroll
            for (int q = 0; q < 4; ++q) {
                float4 bb = *(const float4*)(br + q * 64);
                s = fmaf(av[q].w, bb.w, fmaf(av[q].z, bb.z, fmaf(av[q].y, bb.y, fmaf(av[q].x, bb.x, s))));
            }
#pragma unroll
            for (int d = 1; d < 16; d <<= 1) s += __shfl_xor(s, d, 64);
            if (lg == 0 && s > bv) { bv = s; bi = j; }
        }
#pragma unroll
        for (int d = 16; d < 64; d <<= 1) {
            float ov = __shfl_xor(bv, d, 64);
            int oi = __shfl_xor(bi, d, 64);
            if (ov > bv || (ov == bv && oi < bi)) { bv = ov; bi = oi; }
        }
        if (l == 0) { wv[w] = bv; wi[w] = bi; }
        __syncthreads();
        if (tid == 0) {
            float vm = wv[0]; int im = wi[0];
#pragma unroll
            for (int q = 1; q < 8; ++q)
                if (wv[q] > vm || (wv[q] == vm && wi[q] < im)) { vm = wv[q]; im = wi[q]; }
            int g = im / 3, r = im - 3 * g;
            sel[row] = 4 * g + r + 1;
        }
    }
}

// ---------------- K4a: fuse; one block per (b,c), x-row staged in LDS ----------------
__global__ void k_fuse(const float* __restrict__ x, const int* __restrict__ sel,
                       const float* __restrict__ fwraw, float* __restrict__ F) {
    __shared__ float row[TT];
    int b = blockIdx.y, c = blockIdx.x;
    int tid = threadIdx.x;
    const float* xr = x + ((size_t)b * CC + c) * TT;
#pragma unroll
    for (int r = 0; r < 4; ++r)
        *(float4*)&row[r * 1024 + tid * 4] = *(const float4*)(xr + r * 1024 + tid * 4);
    float w0 = fminf(fmaxf(fwraw[0], 0.f), 6.f);
    float w1 = fminf(fmaxf(fwraw[1], 0.f), 6.f);
    float s = w0 + w1 + 1e-8f;
    float fw0 = w0 / s, fw1 = w1 / s;
    __syncthreads();
    float4 outv;
    float* op = &outv.x;
#pragma unroll
    for (int u = 0; u < 4; ++u) {
        int p = tid * 4 + u;
        int lin = 4 * p;
        int spa = ((lin & 63) == 0) ? lin + 1 : lin - 1;
        int ssim = sel[b * NA + p];
        float xa = row[lin], xs = row[ssim], xp = row[spa];
        float ms = (xa + xs) * 0.5f;
        float mp = (xa + xp) * 0.5f;
        op[u] = fw0 * ms + fw1 * mp;
    }
    *(float4*)(F + ((size_t)b * CC + c) * NA + tid * 4) = outv;
}

// ---------------- K4b: 1x1 conv GEMM + BN + SiLU ----------------
__global__ void __launch_bounds__(256) k_conv(const float* __restrict__ F, const float* __restrict__ W,
                                              const float* __restrict__ gamma, const float* __restrict__ beta,
                                              const float* __restrict__ mean, const float* __restrict__ var,
                                              float* __restrict__ out) {
    __shared__ float Ws[16][68];
    __shared__ float Fs[16][68];
    int b = blockIdx.z;
    int o0 = blockIdx.y * 64;
    int p0 = blockIdx.x * 64;
    int tid = threadIdx.x;
    int tr = tid >> 4, tc = tid & 15;
    int sr = tid >> 2, skb = (tid & 3) * 4;
    int fkk = tid >> 4, fj = (tid & 15) * 4;
    const float* Fb = F + (size_t)b * CC * NA;
    float acc[4][4];
#pragma unroll
    for (int u = 0; u < 4; ++u)
#pragma unroll
        for (int v = 0; v < 4; ++v) acc[u][v] = 0.f;

    for (int kt = 0; kt < CC / 16; ++kt) {
        __syncthreads();
        float4 w4 = *(const float4*)(W + (size_t)(o0 + sr) * CC + kt * 16 + skb);
        Ws[skb + 0][sr] = w4.x; Ws[skb + 1][sr] = w4.y;
        Ws[skb + 2][sr] = w4.z; Ws[skb + 3][sr] = w4.w;
        float4 f4 = *(const float4*)(Fb + (size_t)(kt * 16 + fkk) * NA + p0 + fj);
        *(float4*)&Fs[fkk][fj] = f4;
        __syncthreads();
#pragma unroll
        for (int kk = 0; kk < 16; ++kk) {
            float4 av = *(const float4*)&Ws[kk][tr * 4];
            float4 bv4 = *(const float4*)&Fs[kk][tc * 4];
            float a_[4] = {av.x, av.y, av.z, av.w};
            float b_[4] = {bv4.x, bv4.y, bv4.z, bv4.w};
#pragma unroll
            for (int u = 0; u < 4; ++u)
#pragma unroll
                for (int v = 0; v < 4; ++v)
                    acc[u][v] = fmaf(a_[u], b_[v], acc[u][v]);
        }
    }
#pragma unroll
    for (int u = 0; u < 4; ++u) {
        int o = o0 + tr * 4 + u;
        float sc = gamma[o] / sqrtf(var[o] + 1e-5f);
        float sh = fmaf(-mean[o], sc, beta[o]);
        float4 r;
        float* rp = &r.x;
#pragma unroll
        for (int v = 0; v < 4; ++v) {
            float y = fmaf(acc[u][v], sc, sh);
            rp[v] = y / (1.f + expf(-y));
        }
        *(float4*)(out + ((size_t)b * OC + o) * NA + p0 + tc * 4) = r;
    }
}

extern "C" void kernel_launch(void* const* d_in, const int* in_sizes, int n_in,
                              void* d_out, int out_size, void* d_ws, size_t ws_size,
                              hipStream_t stream) {
    const float* x      = (const float*)d_in[0];
    const float* conv_w = (const float*)d_in[1];
    const float* gamma  = (const float*)d_in[2];
    const float* beta   = (const float*)d_in[3];
    const float* mean   = (const float*)d_in[4];
    const float* var    = (const float*)d_in[5];
    const float* fw     = (const float*)d_in[6];
    float* out = (float*)d_out;

    float* ws    = (float*)d_ws;
    float* norms = ws;                                     // BB*TT f
    float* Ap    = norms + (size_t)BB * TT;                // BB*NA*CC f
    float* Bp    = Ap + (size_t)BB * NA * CC;              // BB*NB*CC f
    float* Pv1   = Bp + (size_t)BB * NB * CC;              // BB*NPART*NA f
    float* Pv2   = Pv1 + (size_t)BB * NPART * NA;          // BB*NPART*NA f
    float* Pv3   = Pv2 + (size_t)BB * NPART * NA;          // BB*NPART*NA f
    int*   Pi1   = (int*)(Pv3 + (size_t)BB * NPART * NA);  // BB*NPART*NA i
    int*   Pi2   = Pi1 + (size_t)BB * NPART * NA;          // BB*NPART*NA i
    int*   sel   = Pi2 + (size_t)BB * NPART * NA;          // BB*NA i
    int*   wl    = sel + (size_t)BB * NA;                  // BB*NA i
    int*   count = wl + (size_t)BB * NA;                   // 1 i
    float* F     = Ap;                                     // reuse Ap region after fallback

    k_norm<<<BB * TT / 256, 256, 0, stream>>>(x, norms);
    k_pack<<<dim3(TT / 64, CC / 64, BB), 256, 0, stream>>>(x, norms, Ap, Bp);
    k_sim<<<dim3(NA / 128, NCH, BB), 256, 0, stream>>>(Ap, Bp, Pv1, Pi1, Pv2, Pi2, Pv3);
    k_zero<<<1, 1, 0, stream>>>(count);
    k_reduce2<<<BB * NA / 256, 256, 0, stream>>>(Pv1, Pi1, Pv2, Pi2, Pv3, Ap, Bp, sel, wl, count);
    k_fallback<<<2048, 512, 0, stream>>>(Ap, Bp, wl, count, sel);
    k_fuse<<<dim3(CC, BB), 256, 0, stream>>>(x, sel, fw, F);
    k_conv<<<dim3(NA / 64, OC / 64, BB), 256, 0, stream>>>(F, conv_w, gamma, beta, mean, var, out);
}

// Round 17
// 297.841 us; speedup vs baseline: 1.0870x; 1.0806x over previous
//
#include <hip/hip_runtime.h>
#include <math.h>

#define BB 16
#define CC 256
#define TT 4096
#define NA 1024
#define NB 3072
#define OC 512

#define NCH 12         // j-chunks for MFMA sim kernel (256 j each = 2 tiles of 128)
#define NPART (NCH*2)  // partials: chunk x wc-half (race-free direct per-wave writes)
#define DELTA 2e-4f    // margin below which a row falls back to exact fp32 argmax

typedef float f32x4 __attribute__((ext_vector_type(4)));
typedef short bf16x8 __attribute__((ext_vector_type(8)));

// ---------------- K1: per-token L2 norm over C (+ worklist counter reset) ----------------
__global__ void k_norm(const float* __restrict__ x, float* __restrict__ norms,
                       int* __restrict__ count) {
    int idx = blockIdx.x * 256 + threadIdx.x;   // b*TT + t
    if (idx == 0) *count = 0;
    int b = idx >> 12;
    int t = idx & 4095;
    const float* xp = x + (size_t)b * CC * TT + t;
    float s = 0.f;
#pragma unroll 16
    for (int c = 0; c < CC; ++c) {
        float v = xp[(size_t)c * TT];
        s = fmaf(v, v, s);
    }
    norms[idx] = sqrtf(s);
}

// ---------------- K2: transpose-pack normalized a/b tokens (fp32 only) ----------------
__global__ void k_pack(const float* __restrict__ x, const float* __restrict__ norms,
                       float* __restrict__ Ap, float* __restrict__ Bp) {
    __shared__ float tile[64][65];
    __shared__ float ns[64];
    int b = blockIdx.z, c0 = blockIdx.y * 64, t0 = blockIdx.x * 64;
    int tid = threadIdx.x;
#pragma unroll
    for (int rep = 0; rep < 16; ++rep) {
        int lin = rep * 256 + tid;
        int i = lin >> 6, j = lin & 63;
        tile[i][j] = x[((size_t)b * CC + c0 + i) * TT + t0 + j];
    }
    if (tid < 64) ns[tid] = norms[b * TT + t0 + tid];
    __syncthreads();
#pragma unroll
    for (int rep = 0; rep < 16; ++rep) {
        int lin = rep * 256 + tid;
        int j = lin >> 6, i = lin & 63;
        int t = t0 + j;
        float v = tile[i][j] / ns[j];
        if ((t & 3) == 0) {
            Ap[((size_t)b * NA + (t >> 2)) * CC + c0 + i] = v;
        } else {
            int g = t >> 2, r = t & 3;
            Bp[((size_t)b * NB + 3 * g + (r - 1)) * CC + c0 + i] = v;
        }
    }
}

// ---------------- K3: MFMA sim; T14 async-STAGE (load-early / split+write-late) ----------------
__device__ inline void split8(float4 p0, float4 p1, bf16x8& hi, bf16x8& lo) {
    float f[8] = {p0.x, p0.y, p0.z, p0.w, p1.x, p1.y, p1.z, p1.w};
#pragma unroll
    for (int j = 0; j < 8; ++j) {
        uint u = __float_as_uint(f[j]);
        hi[j] = (short)(u >> 16);
        float hf = __uint_as_float(u & 0xffff0000u);
        lo[j] = (short)(__float_as_uint(f[j] - hf) >> 16);
    }
}

#define LOADT(SRC_BASE, KT, RG)                                                   \
    _Pragma("unroll")                                                             \
    for (int rep = 0; rep < 4; ++rep) {                                           \
        int lin = rep * 256 + tid;                                                \
        int r = lin >> 3, g = lin & 7;                                            \
        const float* sp = (SRC_BASE) + (size_t)r * CC + (KT) * 64 + g * 8;        \
        RG[rep][0] = *(const float4*)sp;                                          \
        RG[rep][1] = *(const float4*)(sp + 4);                                    \
    }

#define WRITET(RG, DH, DL)                                                        \
    _Pragma("unroll")                                                             \
    for (int rep = 0; rep < 4; ++rep) {                                           \
        int lin = rep * 256 + tid;                                                \
        int r = lin >> 3, g = lin & 7;                                            \
        bf16x8 h8, l8;                                                            \
        split8(RG[rep][0], RG[rep][1], h8, l8);                                   \
        int off = r * 128 + ((g ^ (r & 7)) << 4);                                 \
        *(bf16x8*)((DH) + off) = h8;                                              \
        *(bf16x8*)((DL) + off) = l8;                                              \
    }

#define MFMA_TILE(ACC)                                                            \
    _Pragma("unroll")                                                             \
    for (int ks = 0; ks < 2; ++ks) {                                              \
        bf16x8 ahi[4], alo[4];                                                    \
        _Pragma("unroll")                                                         \
        for (int mf = 0; mf < 4; ++mf) {                                          \
            int ra = wr * 64 + mf * 16 + lr;                                      \
            int offa = ra * 128 + (((ks * 4 + lk) ^ (ra & 7)) << 4);              \
            ahi[mf] = *(const bf16x8*)(Ah + offa);                                \
            alo[mf] = *(const bf16x8*)(Al + offa);                                \
        }                                                                         \
        _Pragma("unroll")                                                         \
        for (int nf = 0; nf < 4; ++nf) {                                          \
            int rb = wc * 64 + nf * 16 + lr;                                      \
            int offb = rb * 128 + (((ks * 4 + lk) ^ (rb & 7)) << 4);              \
            bf16x8 bhi = *(const bf16x8*)(Bh + offb);                             \
            bf16x8 blo = *(const bf16x8*)(Bl + offb);                             \
            _Pragma("unroll")                                                     \
            for (int mf = 0; mf < 4; ++mf) {                                      \
                ACC[mf][nf] = __builtin_amdgcn_mfma_f32_16x16x32_bf16(ahi[mf], blo, ACC[mf][nf], 0, 0, 0); \
                ACC[mf][nf] = __builtin_amdgcn_mfma_f32_16x16x32_bf16(alo[mf], bhi, ACC[mf][nf], 0, 0, 0); \
                ACC[mf][nf] = __builtin_amdgcn_mfma_f32_16x16x32_bf16(ahi[mf], bhi, ACC[mf][nf], 0, 0, 0); \
            }                                                                     \
        }                                                                         \
    }

// per-row top2 over one 128-col tile; D mapping col=lane&15, row=(lane>>4)*4+reg [m89]
#define TOP2(ACC, JBASE)                                                          \
    _Pragma("unroll")                                                             \
    for (int mf = 0; mf < 4; ++mf)                                                \
    _Pragma("unroll")                                                             \
        for (int reg = 0; reg < 4; ++reg) {                                       \
            int q = mf * 4 + reg;                                                 \
            float v1 = ACC[mf][0][reg];                                           \
            int i1 = (JBASE) + wc * 64 + lr;                                      \
            float v2 = -1e30f;                                                    \
            _Pragma("unroll")                                                     \
            for (int nf = 1; nf < 4; ++nf) {                                      \
                float xv = ACC[mf][nf][reg];                                      \
                int xi = (JBASE) + wc * 64 + nf * 16 + lr;                        \
                if (xv > v1) { v2 = v1; v1 = xv; i1 = xi; }                       \
                else v2 = fmaxf(v2, xv);                                          \
            }                                                                     \
            _Pragma("unroll")                                                     \
            for (int d = 1; d < 16; d <<= 1) {                                    \
                float ov1 = __shfl_xor(v1, d, 64);                                \
                int oi1 = __shfl_xor(i1, d, 64);                                  \
                float ov2 = __shfl_xor(v2, d, 64);                                \
                bool take = (ov1 > v1) || (ov1 == v1 && oi1 < i1);                \
                float bw = take ? v1 : ov1;                                       \
                v2 = fmaxf(fmaxf(v2, ov2), bw);                                   \
                if (take) { v1 = ov1; i1 = oi1; }                                 \
            }                                                                     \
            bool t2 = (v1 > rv1[q]);                                              \
            float bw2 = t2 ? rv1[q] : v1;                                         \
            rv2[q] = fmaxf(fmaxf(rv2[q], v2), bw2);                               \
            if (t2) { rv1[q] = v1; ri1[q] = i1; }                                 \
        }

__global__ void __launch_bounds__(256, 2) k_sim(const float* __restrict__ Ap,
                                                const float* __restrict__ Bp,
                                                float* __restrict__ Pv1, int* __restrict__ Pi1,
                                                float* __restrict__ Pv2) {
    __shared__ __align__(16) char lds[65536];   // Ah|Al|Bh|Bl, 16KB each ([128][64] bf16 swizzled)
    char* Ah = lds;
    char* Al = lds + 16384;
    char* Bh = lds + 32768;
    char* Bl = lds + 49152;
    const int b = blockIdx.z;
    const int ch = blockIdx.y;
    const int i0 = blockIdx.x * 128;
    const int tid = threadIdx.x;
    const int l = tid & 63, wid = tid >> 6;
    const int wr = wid >> 1, wc = wid & 1;      // 2x2 wave grid, 64x64 per wave per tile
    const int lr = l & 15, lk = l >> 4;
    const float* Abase = Ap + ((size_t)b * NA + i0) * CC;
    const float* Bbase = Bp + (size_t)b * NB * CC;
    const int j0c = ch * 256;

    float rv1[16], rv2[16];
    int ri1[16];
#pragma unroll
    for (int q = 0; q < 16; ++q) { rv1[q] = -1e30f; rv2[q] = -1e30f; ri1[q] = 0; }

    f32x4 acc0[4][4], acc1[4][4];
#pragma unroll
    for (int mf = 0; mf < 4; ++mf)
#pragma unroll
        for (int nf = 0; nf < 4; ++nf) {
            acc0[mf][nf] = (f32x4){0.f, 0.f, 0.f, 0.f};
            acc1[mf][nf] = (f32x4){0.f, 0.f, 0.f, 0.f};
        }

    float4 rA[4][2], rB[4][2];
    LOADT(Abase, 0, rA)
    LOADT(Bbase + (size_t)j0c * CC, 0, rB)

    for (int kt = 0; kt < 4; ++kt) {
        __syncthreads();                      // prior tile reads done
        WRITET(rA, Ah, Al)                    // split+write prefetched A,B1
        WRITET(rB, Bh, Bl)
        __syncthreads();
        LOADT(Bbase + (size_t)(j0c + 128) * CC, kt, rB)   // issue B2 loads under MFMA0
        MFMA_TILE(acc0)
        __syncthreads();                      // MFMA0 done reading Bh/Bl
        WRITET(rB, Bh, Bl)
        __syncthreads();
        if (kt < 3) {                         // issue next-kt A,B1 loads under MFMA1
            LOADT(Abase, kt + 1, rA)
            LOADT(Bbase + (size_t)j0c * CC, kt + 1, rB)
        }
        MFMA_TILE(acc1)
    }

    TOP2(acc0, j0c)                           // ascending j: tile0 then tile1
    TOP2(acc1, j0c + 128)

    // race-free: each wave writes its own (chunk, wc-half) partial
    if (lr == 0) {
        int pch = ch * 2 + wc;
#pragma unroll
        for (int mf = 0; mf < 4; ++mf)
#pragma unroll
            for (int reg = 0; reg < 4; ++reg) {
                int row = i0 + wr * 64 + mf * 16 + lk * 4 + reg;
                size_t o = ((size_t)b * NPART + pch) * NA + row;
                int q = mf * 4 + reg;
                Pv1[o] = rv1[q]; Pi1[o] = ri1[q]; Pv2[o] = rv2[q];
            }
    }
}

// ---------------- K3b: merge partials -> sel + compact flagged worklist ----------------
__global__ void k_reduce2(const float* __restrict__ Pv1, const int* __restrict__ Pi1,
                          const float* __restrict__ Pv2, int* __restrict__ sel,
                          int* __restrict__ wl, int* __restrict__ count) {
    int idx = blockIdx.x * 256 + threadIdx.x;   // b*NA + a
    int b = idx >> 10;
    int a = idx & 1023;
    float v1 = -1e30f, v2 = -1e30f;
    int i1 = 0x7fffffff;
#pragma unroll
    for (int pc = 0; pc < NPART; ++pc) {
        size_t o = ((size_t)b * NPART + pc) * NA + a;
        float nv1 = Pv1[o];
        int ni1 = Pi1[o];
        bool take = (nv1 > v1) || (nv1 == v1 && ni1 < i1);
        float bw = take ? v1 : nv1;
        v2 = fmaxf(fmaxf(v2, Pv2[o]), bw);
        if (take) { v1 = nv1; i1 = ni1; }
    }
    int g = i1 / 3, r = i1 - 3 * g;
    sel[idx] = 4 * g + r + 1;
    if (v1 - v2 < DELTA) {
        int p = atomicAdd(count, 1);
        wl[p] = idx;
    }
}

// ---------------- K3c: exact fp32 re-argmax for flagged rows (worklist) ----------------
__global__ void __launch_bounds__(512) k_fallback(const float* __restrict__ Ap,
                                                  const float* __restrict__ Bp,
                                                  const int* __restrict__ wl,
                                                  const int* __restrict__ count,
                                                  int* __restrict__ sel) {
    int n = *count;
    __shared__ float arow[CC];
    __shared__ float wv[8];
    __shared__ int wi[8];
    int tid = threadIdx.x;                // 512 threads = 8 waves
    int l = tid & 63, w = tid >> 6;
    int lg = l & 15, grp = l >> 4;
    for (int it = blockIdx.x; it < n; it += gridDim.x) {
        int row = wl[it];
        int b = row >> 10, a = row & 1023;
        __syncthreads();                  // protect arow/wv reuse across iterations
        if (tid < 64) *(float4*)&arow[tid * 4] = *(const float4*)(Ap + ((size_t)b * NA + a) * CC + tid * 4);
        __syncthreads();
        float4 av[4];
#pragma unroll
        for (int q = 0; q < 4; ++q) av[q] = *(const float4*)&arow[q * 64 + lg * 4];
        const float* Bb = Bp + (size_t)b * NB * CC;
        float bv = -1e30f;
        int bi = 0;
        for (int j = w * 4 + grp; j < NB; j += 32) {
            const float* br = Bb + (size_t)j * CC + lg * 4;
            float s = 0.f;
#pragma unroll
            for (int q = 0; q < 4; ++q) {
                float4 bb = *(const float4*)(br + q * 64);
                s = fmaf(av[q].w, bb.w, fmaf(av[q].z, bb.z, fmaf(av[q].y, bb.y, fmaf(av[q].x, bb.x, s))));
            }
#pragma unroll
            for (int d = 1; d < 16; d <<= 1) s += __shfl_xor(s, d, 64);
            if (lg == 0 && s > bv) { bv = s; bi = j; }   // ascending per group-lead
        }
#pragma unroll
        for (int d = 16; d < 64; d <<= 1) {
            float ov = __shfl_xor(bv, d, 64);
            int oi = __shfl_xor(bi, d, 64);
            if (ov > bv || (ov == bv && oi < bi)) { bv = ov; bi = oi; }
        }
        if (l == 0) { wv[w] = bv; wi[w] = bi; }
        __syncthreads();
        if (tid == 0) {
            float vm = wv[0]; int im = wi[0];
#pragma unroll
            for (int q = 1; q < 8; ++q)
                if (wv[q] > vm || (wv[q] == vm && wi[q] < im)) { vm = wv[q]; im = wi[q]; }
            int g = im / 3, r = im - 3 * g;
            sel[row] = 4 * g + r + 1;
        }
    }
}

// ---------------- K4a: fuse; one block per (b,c), x-row staged in LDS ----------------
__global__ void k_fuse(const float* __restrict__ x, const int* __restrict__ sel,
                       const float* __restrict__ fwraw, float* __restrict__ F) {
    __shared__ float row[TT];
    int b = blockIdx.y, c = blockIdx.x;
    int tid = threadIdx.x;
    const float* xr = x + ((size_t)b * CC + c) * TT;
#pragma unroll
    for (int r = 0; r < 4; ++r)
        *(float4*)&row[r * 1024 + tid * 4] = *(const float4*)(xr + r * 1024 + tid * 4);
    float w0 = fminf(fmaxf(fwraw[0], 0.f), 6.f);
    float w1 = fminf(fmaxf(fwraw[1], 0.f), 6.f);
    float s = w0 + w1 + 1e-8f;
    float fw0 = w0 / s, fw1 = w1 / s;
    __syncthreads();
    float4 outv;
    float* op = &outv.x;
#pragma unroll
    for (int u = 0; u < 4; ++u) {
        int p = tid * 4 + u;
        int lin = 4 * p;
        int spa = ((lin & 63) == 0) ? lin + 1 : lin - 1;
        int ssim = sel[b * NA + p];
        float xa = row[lin], xs = row[ssim], xp = row[spa];
        float ms = (xa + xs) * 0.5f;
        float mp = (xa + xp) * 0.5f;
        op[u] = fw0 * ms + fw1 * mp;
    }
    *(float4*)(F + ((size_t)b * CC + c) * NA + tid * 4) = outv;
}

// ---------------- K4b: 1x1 conv GEMM + BN + SiLU ----------------
__global__ void __launch_bounds__(256) k_conv(const float* __restrict__ F, const float* __restrict__ W,
                                              const float* __restrict__ gamma, const float* __restrict__ beta,
                                              const float* __restrict__ mean, const float* __restrict__ var,
                                              float* __restrict__ out) {
    __shared__ float Ws[16][68];
    __shared__ float Fs[16][68];
    int b = blockIdx.z;
    int o0 = blockIdx.y * 64;
    int p0 = blockIdx.x * 64;
    int tid = threadIdx.x;
    int tr = tid >> 4, tc = tid & 15;
    int sr = tid >> 2, skb = (tid & 3) * 4;
    int fkk = tid >> 4, fj = (tid & 15) * 4;
    const float* Fb = F + (size_t)b * CC * NA;
    float acc[4][4];
#pragma unroll
    for (int u = 0; u < 4; ++u)
#pragma unroll
        for (int v = 0; v < 4; ++v) acc[u][v] = 0.f;

    for (int kt = 0; kt < CC / 16; ++kt) {
        __syncthreads();
        float4 w4 = *(const float4*)(W + (size_t)(o0 + sr) * CC + kt * 16 + skb);
        Ws[skb + 0][sr] = w4.x; Ws[skb + 1][sr] = w4.y;
        Ws[skb + 2][sr] = w4.z; Ws[skb + 3][sr] = w4.w;
        float4 f4 = *(const float4*)(Fb + (size_t)(kt * 16 + fkk) * NA + p0 + fj);
        *(float4*)&Fs[fkk][fj] = f4;
        __syncthreads();
#pragma unroll
        for (int kk = 0; kk < 16; ++kk) {
            float4 av = *(const float4*)&Ws[kk][tr * 4];
            float4 bv4 = *(const float4*)&Fs[kk][tc * 4];
            float a_[4] = {av.x, av.y, av.z, av.w};
            float b_[4] = {bv4.x, bv4.y, bv4.z, bv4.w};
#pragma unroll
            for (int u = 0; u < 4; ++u)
#pragma unroll
                for (int v = 0; v < 4; ++v)
                    acc[u][v] = fmaf(a_[u], b_[v], acc[u][v]);
        }
    }
#pragma unroll
    for (int u = 0; u < 4; ++u) {
        int o = o0 + tr * 4 + u;
        float sc = gamma[o] / sqrtf(var[o] + 1e-5f);
        float sh = fmaf(-mean[o], sc, beta[o]);
        float4 r;
        float* rp = &r.x;
#pragma unroll
        for (int v = 0; v < 4; ++v) {
            float y = fmaf(acc[u][v], sc, sh);
            rp[v] = y / (1.f + expf(-y));
        }
        *(float4*)(out + ((size_t)b * OC + o) * NA + p0 + tc * 4) = r;
    }
}

extern "C" void kernel_launch(void* const* d_in, const int* in_sizes, int n_in,
                              void* d_out, int out_size, void* d_ws, size_t ws_size,
                              hipStream_t stream) {
    const float* x      = (const float*)d_in[0];
    const float* conv_w = (const float*)d_in[1];
    const float* gamma  = (const float*)d_in[2];
    const float* beta   = (const float*)d_in[3];
    const float* mean   = (const float*)d_in[4];
    const float* var    = (const float*)d_in[5];
    const float* fw     = (const float*)d_in[6];
    float* out = (float*)d_out;

    float* ws    = (float*)d_ws;
    float* norms = ws;                                     // BB*TT f
    float* Ap    = norms + (size_t)BB * TT;                // BB*NA*CC f
    float* Bp    = Ap + (size_t)BB * NA * CC;              // BB*NB*CC f
    float* Pv1   = Bp + (size_t)BB * NB * CC;              // BB*NPART*NA f
    float* Pv2   = Pv1 + (size_t)BB * NPART * NA;          // BB*NPART*NA f
    int*   Pi1   = (int*)(Pv2 + (size_t)BB * NPART * NA);  // BB*NPART*NA i
    int*   sel   = Pi1 + (size_t)BB * NPART * NA;          // BB*NA i
    int*   wl    = sel + (size_t)BB * NA;                  // BB*NA i
    int*   count = wl + (size_t)BB * NA;                   // 1 i
    float* F     = Ap;                                     // reuse Ap region after fallback

    k_norm<<<BB * TT / 256, 256, 0, stream>>>(x, norms, count);
    k_pack<<<dim3(TT / 64, CC / 64, BB), 256, 0, stream>>>(x, norms, Ap, Bp);
    k_sim<<<dim3(NA / 128, NCH, BB), 256, 0, stream>>>(Ap, Bp, Pv1, Pi1, Pv2);
    k_reduce2<<<BB * NA / 256, 256, 0, stream>>>(Pv1, Pi1, Pv2, sel, wl, count);
    k_fallback<<<2048, 512, 0, stream>>>(Ap, Bp, wl, count, sel);
    k_fuse<<<dim3(CC, BB), 256, 0, stream>>>(x, sel, fw, F);
    k_conv<<<dim3(NA / 64, OC / 64, BB), 256, 0, stream>>>(F, conv_w, gamma, beta, mean, var, out);
}

// Round 18
// 296.703 us; speedup vs baseline: 1.0911x; 1.0038x over previous
//
#include <hip/hip_runtime.h>
#include <math.h>

#define BB 16
#define CC 256
#define TT 4096
#define NA 1024
#define NB 3072
#define OC 512

#define NCH 12         // j-chunks for MFMA sim kernel (256 j each = 2 tiles of 128)
#define NPART (NCH*2)  // partials: chunk x wc-half (race-free direct per-wave writes)
#define DELTA 2e-4f    // margin below which a row falls back to exact fp32 argmax
#define NTOK (BB*TT)   // 65536 tokens

typedef float f32x4 __attribute__((ext_vector_type(4)));
typedef short bf16x8 __attribute__((ext_vector_type(8)));

// ---------------- K1: sum-of-squares partials, float4 over t, C split 4x64 ----------------
__global__ void k_norm(const float* __restrict__ x, float* __restrict__ norms4,
                       int* __restrict__ count) {
    int id = blockIdx.x * 256 + threadIdx.x;    // 65536 threads: chunk x token-quad
    if (id == 0) *count = 0;
    int chunk = id >> 14;                       // 4 c-chunks
    int qid = id & 16383;                       // b*1024 + t4
    int b = qid >> 10;
    int t4 = qid & 1023;
    const float* xp = x + ((size_t)b * CC + chunk * 64) * TT + t4 * 4;
    float4 s = {0.f, 0.f, 0.f, 0.f};
#pragma unroll 16
    for (int c = 0; c < 64; ++c) {
        float4 v = *(const float4*)(xp + (size_t)c * TT);
        s.x = fmaf(v.x, v.x, s.x);
        s.y = fmaf(v.y, v.y, s.y);
        s.z = fmaf(v.z, v.z, s.z);
        s.w = fmaf(v.w, v.w, s.w);
    }
    *(float4*)(norms4 + (size_t)chunk * NTOK + (size_t)qid * 4) = s;
}

// ---------------- K2: transpose-pack normalized a/b tokens (fp32 only) ----------------
__global__ void k_pack(const float* __restrict__ x, const float* __restrict__ norms4,
                       float* __restrict__ Ap, float* __restrict__ Bp) {
    __shared__ float tile[64][65];
    __shared__ float ns[64];
    int b = blockIdx.z, c0 = blockIdx.y * 64, t0 = blockIdx.x * 64;
    int tid = threadIdx.x;
#pragma unroll
    for (int rep = 0; rep < 16; ++rep) {
        int lin = rep * 256 + tid;
        int i = lin >> 6, j = lin & 63;
        tile[i][j] = x[((size_t)b * CC + c0 + i) * TT + t0 + j];
    }
    if (tid < 64) {
        int tok = b * TT + t0 + tid;
        float p = norms4[tok] + norms4[NTOK + tok] + norms4[2 * NTOK + tok] + norms4[3 * NTOK + tok];
        ns[tid] = sqrtf(p);
    }
    __syncthreads();
#pragma unroll
    for (int rep = 0; rep < 16; ++rep) {
        int lin = rep * 256 + tid;
        int j = lin >> 6, i = lin & 63;
        int t = t0 + j;
        float v = tile[i][j] / ns[j];
        if ((t & 3) == 0) {
            Ap[((size_t)b * NA + (t >> 2)) * CC + c0 + i] = v;
        } else {
            int g = t >> 2, r = t & 3;
            Bp[((size_t)b * NB + 3 * g + (r - 1)) * CC + c0 + i] = v;
        }
    }
}

// ---------------- K3: MFMA sim; T14 async-STAGE (load-early / split+write-late) ----------------
__device__ inline void split8(float4 p0, float4 p1, bf16x8& hi, bf16x8& lo) {
    float f[8] = {p0.x, p0.y, p0.z, p0.w, p1.x, p1.y, p1.z, p1.w};
#pragma unroll
    for (int j = 0; j < 8; ++j) {
        uint u = __float_as_uint(f[j]);
        hi[j] = (short)(u >> 16);
        float hf = __uint_as_float(u & 0xffff0000u);
        lo[j] = (short)(__float_as_uint(f[j] - hf) >> 16);
    }
}

#define LOADT(SRC_BASE, KT, RG)                                                   \
    _Pragma("unroll")                                                             \
    for (int rep = 0; rep < 4; ++rep) {                                           \
        int lin = rep * 256 + tid;                                                \
        int r = lin >> 3, g = lin & 7;                                            \
        const float* sp = (SRC_BASE) + (size_t)r * CC + (KT) * 64 + g * 8;        \
        RG[rep][0] = *(const float4*)sp;                                          \
        RG[rep][1] = *(const float4*)(sp + 4);                                    \
    }

#define WRITET(RG, DH, DL)                                                        \
    _Pragma("unroll")                                                             \
    for (int rep = 0; rep < 4; ++rep) {                                           \
        int lin = rep * 256 + tid;                                                \
        int r = lin >> 3, g = lin & 7;                                            \
        bf16x8 h8, l8;                                                            \
        split8(RG[rep][0], RG[rep][1], h8, l8);                                   \
        int off = r * 128 + ((g ^ (r & 7)) << 4);                                 \
        *(bf16x8*)((DH) + off) = h8;                                              \
        *(bf16x8*)((DL) + off) = l8;                                              \
    }

#define MFMA_TILE(ACC)                                                            \
    _Pragma("unroll")                                                             \
    for (int ks = 0; ks < 2; ++ks) {                                              \
        bf16x8 ahi[4], alo[4];                                                    \
        _Pragma("unroll")                                                         \
        for (int mf = 0; mf < 4; ++mf) {                                          \
            int ra = wr * 64 + mf * 16 + lr;                                      \
            int offa = ra * 128 + (((ks * 4 + lk) ^ (ra & 7)) << 4);              \
            ahi[mf] = *(const bf16x8*)(Ah + offa);                                \
            alo[mf] = *(const bf16x8*)(Al + offa);                                \
        }                                                                         \
        _Pragma("unroll")                                                         \
        for (int nf = 0; nf < 4; ++nf) {                                          \
            int rb = wc * 64 + nf * 16 + lr;                                      \
            int offb = rb * 128 + (((ks * 4 + lk) ^ (rb & 7)) << 4);              \
            bf16x8 bhi = *(const bf16x8*)(Bh + offb);                             \
            bf16x8 blo = *(const bf16x8*)(Bl + offb);                             \
            _Pragma("unroll")                                                     \
            for (int mf = 0; mf < 4; ++mf) {                                      \
                ACC[mf][nf] = __builtin_amdgcn_mfma_f32_16x16x32_bf16(ahi[mf], blo, ACC[mf][nf], 0, 0, 0); \
                ACC[mf][nf] = __builtin_amdgcn_mfma_f32_16x16x32_bf16(alo[mf], bhi, ACC[mf][nf], 0, 0, 0); \
                ACC[mf][nf] = __builtin_amdgcn_mfma_f32_16x16x32_bf16(ahi[mf], bhi, ACC[mf][nf], 0, 0, 0); \
            }                                                                     \
        }                                                                         \
    }

// per-row top2 over one 128-col tile; D mapping col=lane&15, row=(lane>>4)*4+reg [m89]
#define TOP2(ACC, JBASE)                                                          \
    _Pragma("unroll")                                                             \
    for (int mf = 0; mf < 4; ++mf)                                                \
    _Pragma("unroll")                                                             \
        for (int reg = 0; reg < 4; ++reg) {                                       \
            int q = mf * 4 + reg;                                                 \
            float v1 = ACC[mf][0][reg];                                           \
            int i1 = (JBASE) + wc * 64 + lr;                                      \
            float v2 = -1e30f;                                                    \
            _Pragma("unroll")                                                     \
            for (int nf = 1; nf < 4; ++nf) {                                      \
                float xv = ACC[mf][nf][reg];                                      \
                int xi = (JBASE) + wc * 64 + nf * 16 + lr;                        \
                if (xv > v1) { v2 = v1; v1 = xv; i1 = xi; }                       \
                else v2 = fmaxf(v2, xv);                                          \
            }                                                                     \
            _Pragma("unroll")                                                     \
            for (int d = 1; d < 16; d <<= 1) {                                    \
                float ov1 = __shfl_xor(v1, d, 64);                                \
                int oi1 = __shfl_xor(i1, d, 64);                                  \
                float ov2 = __shfl_xor(v2, d, 64);                                \
                bool take = (ov1 > v1) || (ov1 == v1 && oi1 < i1);                \
                float bw = take ? v1 : ov1;                                       \
                v2 = fmaxf(fmaxf(v2, ov2), bw);                                   \
                if (take) { v1 = ov1; i1 = oi1; }                                 \
            }                                                                     \
            bool t2 = (v1 > rv1[q]);                                              \
            float bw2 = t2 ? rv1[q] : v1;                                         \
            rv2[q] = fmaxf(fmaxf(rv2[q], v2), bw2);                               \
            if (t2) { rv1[q] = v1; ri1[q] = i1; }                                 \
        }

__global__ void __launch_bounds__(256, 2) k_sim(const float* __restrict__ Ap,
                                                const float* __restrict__ Bp,
                                                float* __restrict__ Pv1, int* __restrict__ Pi1,
                                                float* __restrict__ Pv2) {
    __shared__ __align__(16) char lds[65536];   // Ah|Al|Bh|Bl, 16KB each ([128][64] bf16 swizzled)
    char* Ah = lds;
    char* Al = lds + 16384;
    char* Bh = lds + 32768;
    char* Bl = lds + 49152;
    const int b = blockIdx.z;
    const int ch = blockIdx.y;
    const int i0 = blockIdx.x * 128;
    const int tid = threadIdx.x;
    const int l = tid & 63, wid = tid >> 6;
    const int wr = wid >> 1, wc = wid & 1;      // 2x2 wave grid, 64x64 per wave per tile
    const int lr = l & 15, lk = l >> 4;
    const float* Abase = Ap + ((size_t)b * NA + i0) * CC;
    const float* Bbase = Bp + (size_t)b * NB * CC;
    const int j0c = ch * 256;

    float rv1[16], rv2[16];
    int ri1[16];
#pragma unroll
    for (int q = 0; q < 16; ++q) { rv1[q] = -1e30f; rv2[q] = -1e30f; ri1[q] = 0; }

    f32x4 acc0[4][4], acc1[4][4];
#pragma unroll
    for (int mf = 0; mf < 4; ++mf)
#pragma unroll
        for (int nf = 0; nf < 4; ++nf) {
            acc0[mf][nf] = (f32x4){0.f, 0.f, 0.f, 0.f};
            acc1[mf][nf] = (f32x4){0.f, 0.f, 0.f, 0.f};
        }

    float4 rA[4][2], rB[4][2];
    LOADT(Abase, 0, rA)
    LOADT(Bbase + (size_t)j0c * CC, 0, rB)

    for (int kt = 0; kt < 4; ++kt) {
        __syncthreads();                      // prior tile reads done
        WRITET(rA, Ah, Al)                    // split+write prefetched A,B1
        WRITET(rB, Bh, Bl)
        __syncthreads();
        LOADT(Bbase + (size_t)(j0c + 128) * CC, kt, rB)   // issue B2 loads under MFMA0
        __builtin_amdgcn_s_setprio(1);
        MFMA_TILE(acc0)
        __builtin_amdgcn_s_setprio(0);
        __syncthreads();                      // MFMA0 done reading Bh/Bl
        WRITET(rB, Bh, Bl)
        __syncthreads();
        if (kt < 3) {                         // issue next-kt A,B1 loads under MFMA1
            LOADT(Abase, kt + 1, rA)
            LOADT(Bbase + (size_t)j0c * CC, kt + 1, rB)
        }
        __builtin_amdgcn_s_setprio(1);
        MFMA_TILE(acc1)
        __builtin_amdgcn_s_setprio(0);
    }

    TOP2(acc0, j0c)                           // ascending j: tile0 then tile1
    TOP2(acc1, j0c + 128)

    // race-free: each wave writes its own (chunk, wc-half) partial
    if (lr == 0) {
        int pch = ch * 2 + wc;
#pragma unroll
        for (int mf = 0; mf < 4; ++mf)
#pragma unroll
            for (int reg = 0; reg < 4; ++reg) {
                int row = i0 + wr * 64 + mf * 16 + lk * 4 + reg;
                size_t o = ((size_t)b * NPART + pch) * NA + row;
                int q = mf * 4 + reg;
                Pv1[o] = rv1[q]; Pi1[o] = ri1[q]; Pv2[o] = rv2[q];
            }
    }
}

// ---------------- K3b: merge partials -> sel + compact flagged worklist ----------------
__global__ void k_reduce2(const float* __restrict__ Pv1, const int* __restrict__ Pi1,
                          const float* __restrict__ Pv2, int* __restrict__ sel,
                          int* __restrict__ wl, int* __restrict__ count) {
    int idx = blockIdx.x * 256 + threadIdx.x;   // b*NA + a
    int b = idx >> 10;
    int a = idx & 1023;
    float v1 = -1e30f, v2 = -1e30f;
    int i1 = 0x7fffffff;
#pragma unroll
    for (int pc = 0; pc < NPART; ++pc) {
        size_t o = ((size_t)b * NPART + pc) * NA + a;
        float nv1 = Pv1[o];
        int ni1 = Pi1[o];
        bool take = (nv1 > v1) || (nv1 == v1 && ni1 < i1);
        float bw = take ? v1 : nv1;
        v2 = fmaxf(fmaxf(v2, Pv2[o]), bw);
        if (take) { v1 = nv1; i1 = ni1; }
    }
    int g = i1 / 3, r = i1 - 3 * g;
    sel[idx] = 4 * g + r + 1;
    if (v1 - v2 < DELTA) {
        int p = atomicAdd(count, 1);
        wl[p] = idx;
    }
}

// ---------------- K3c: exact fp32 re-argmax for flagged rows (worklist) ----------------
__global__ void __launch_bounds__(512) k_fallback(const float* __restrict__ Ap,
                                                  const float* __restrict__ Bp,
                                                  const int* __restrict__ wl,
                                                  const int* __restrict__ count,
                                                  int* __restrict__ sel) {
    int n = *count;
    __shared__ float arow[CC];
    __shared__ float wv[8];
    __shared__ int wi[8];
    int tid = threadIdx.x;                // 512 threads = 8 waves
    int l = tid & 63, w = tid >> 6;
    int lg = l & 15, grp = l >> 4;
    for (int it = blockIdx.x; it < n; it += gridDim.x) {
        int row = wl[it];
        int b = row >> 10, a = row & 1023;
        __syncthreads();                  // protect arow/wv reuse across iterations
        if (tid < 64) *(float4*)&arow[tid * 4] = *(const float4*)(Ap + ((size_t)b * NA + a) * CC + tid * 4);
        __syncthreads();
        float4 av[4];
#pragma unroll
        for (int q = 0; q < 4; ++q) av[q] = *(const float4*)&arow[q * 64 + lg * 4];
        const float* Bb = Bp + (size_t)b * NB * CC;
        float bv = -1e30f;
        int bi = 0;
        for (int j = w * 4 + grp; j < NB; j += 32) {
            const float* br = Bb + (size_t)j * CC + lg * 4;
            float s = 0.f;
#pragma unroll
            for (int q = 0; q < 4; ++q) {
                float4 bb = *(const float4*)(br + q * 64);
                s = fmaf(av[q].w, bb.w, fmaf(av[q].z, bb.z, fmaf(av[q].y, bb.y, fmaf(av[q].x, bb.x, s))));
            }
#pragma unroll
            for (int d = 1; d < 16; d <<= 1) s += __shfl_xor(s, d, 64);
            if (lg == 0 && s > bv) { bv = s; bi = j; }   // ascending per group-lead
        }
#pragma unroll
        for (int d = 16; d < 64; d <<= 1) {
            float ov = __shfl_xor(bv, d, 64);
            int oi = __shfl_xor(bi, d, 64);
            if (ov > bv || (ov == bv && oi < bi)) { bv = ov; bi = oi; }
        }
        if (l == 0) { wv[w] = bv; wi[w] = bi; }
        __syncthreads();
        if (tid == 0) {
            float vm = wv[0]; int im = wi[0];
#pragma unroll
            for (int q = 1; q < 8; ++q)
                if (wv[q] > vm || (wv[q] == vm && wi[q] < im)) { vm = wv[q]; im = wi[q]; }
            int g = im / 3, r = im - 3 * g;
            sel[row] = 4 * g + r + 1;
        }
    }
}

// ---------------- K4a: fuse; one block per (b,c), x-row staged in LDS ----------------
__global__ void k_fuse(const float* __restrict__ x, const int* __restrict__ sel,
                       const float* __restrict__ fwraw, float* __restrict__ F) {
    __shared__ float row[TT];
    int b = blockIdx.y, c = blockIdx.x;
    int tid = threadIdx.x;
    const float* xr = x + ((size_t)b * CC + c) * TT;
#pragma unroll
    for (int r = 0; r < 4; ++r)
        *(float4*)&row[r * 1024 + tid * 4] = *(const float4*)(xr + r * 1024 + tid * 4);
    float w0 = fminf(fmaxf(fwraw[0], 0.f), 6.f);
    float w1 = fminf(fmaxf(fwraw[1], 0.f), 6.f);
    float s = w0 + w1 + 1e-8f;
    float fw0 = w0 / s, fw1 = w1 / s;
    __syncthreads();
    float4 outv;
    float* op = &outv.x;
#pragma unroll
    for (int u = 0; u < 4; ++u) {
        int p = tid * 4 + u;
        int lin = 4 * p;
        int spa = ((lin & 63) == 0) ? lin + 1 : lin - 1;
        int ssim = sel[b * NA + p];
        float xa = row[lin], xs = row[ssim], xp = row[spa];
        float ms = (xa + xs) * 0.5f;
        float mp = (xa + xp) * 0.5f;
        op[u] = fw0 * ms + fw1 * mp;
    }
    *(float4*)(F + ((size_t)b * CC + c) * NA + tid * 4) = outv;
}

// ---------------- K4b: 1x1 conv GEMM + BN + SiLU ----------------
__global__ void __launch_bounds__(256) k_conv(const float* __restrict__ F, const float* __restrict__ W,
                                              const float* __restrict__ gamma, const float* __restrict__ beta,
                                              const float* __restrict__ mean, const float* __restrict__ var,
                                              float* __restrict__ out) {
    __shared__ float Ws[16][68];
    __shared__ float Fs[16][68];
    int b = blockIdx.z;
    int o0 = blockIdx.y * 64;
    int p0 = blockIdx.x * 64;
    int tid = threadIdx.x;
    int tr = tid >> 4, tc = tid & 15;
    int sr = tid >> 2, skb = (tid & 3) * 4;
    int fkk = tid >> 4, fj = (tid & 15) * 4;
    const float* Fb = F + (size_t)b * CC * NA;
    float acc[4][4];
#pragma unroll
    for (int u = 0; u < 4; ++u)
#pragma unroll
        for (int v = 0; v < 4; ++v) acc[u][v] = 0.f;

    for (int kt = 0; kt < CC / 16; ++kt) {
        __syncthreads();
        float4 w4 = *(const float4*)(W + (size_t)(o0 + sr) * CC + kt * 16 + skb);
        Ws[skb + 0][sr] = w4.x; Ws[skb + 1][sr] = w4.y;
        Ws[skb + 2][sr] = w4.z; Ws[skb + 3][sr] = w4.w;
        float4 f4 = *(const float4*)(Fb + (size_t)(kt * 16 + fkk) * NA + p0 + fj);
        *(float4*)&Fs[fkk][fj] = f4;
        __syncthreads();
#pragma unroll
        for (int kk = 0; kk < 16; ++kk) {
            float4 av = *(const float4*)&Ws[kk][tr * 4];
            float4 bv4 = *(const float4*)&Fs[kk][tc * 4];
            float a_[4] = {av.x, av.y, av.z, av.w};
            float b_[4] = {bv4.x, bv4.y, bv4.z, bv4.w};
#pragma unroll
            for (int u = 0; u < 4; ++u)
#pragma unroll
                for (int v = 0; v < 4; ++v)
                    acc[u][v] = fmaf(a_[u], b_[v], acc[u][v]);
        }
    }
#pragma unroll
    for (int u = 0; u < 4; ++u) {
        int o = o0 + tr * 4 + u;
        float sc = gamma[o] / sqrtf(var[o] + 1e-5f);
        float sh = fmaf(-mean[o], sc, beta[o]);
        float4 r;
        float* rp = &r.x;
#pragma unroll
        for (int v = 0; v < 4; ++v) {
            float y = fmaf(acc[u][v], sc, sh);
            rp[v] = y / (1.f + expf(-y));
        }
        *(float4*)(out + ((size_t)b * OC + o) * NA + p0 + tc * 4) = r;
    }
}

extern "C" void kernel_launch(void* const* d_in, const int* in_sizes, int n_in,
                              void* d_out, int out_size, void* d_ws, size_t ws_size,
                              hipStream_t stream) {
    const float* x      = (const float*)d_in[0];
    const float* conv_w = (const float*)d_in[1];
    const float* gamma  = (const float*)d_in[2];
    const float* beta   = (const float*)d_in[3];
    const float* mean   = (const float*)d_in[4];
    const float* var    = (const float*)d_in[5];
    const float* fw     = (const float*)d_in[6];
    float* out = (float*)d_out;

    float* ws     = (float*)d_ws;
    float* norms4 = ws;                                      // 4*NTOK f
    float* Ap     = norms4 + (size_t)4 * NTOK;               // BB*NA*CC f
    float* Bp     = Ap + (size_t)BB * NA * CC;               // BB*NB*CC f
    float* Pv1    = Bp + (size_t)BB * NB * CC;               // BB*NPART*NA f
    float* Pv2    = Pv1 + (size_t)BB * NPART * NA;           // BB*NPART*NA f
    int*   Pi1    = (int*)(Pv2 + (size_t)BB * NPART * NA);   // BB*NPART*NA i
    int*   sel    = Pi1 + (size_t)BB * NPART * NA;           // BB*NA i
    int*   wl     = sel + (size_t)BB * NA;                   // BB*NA i
    int*   count  = wl + (size_t)BB * NA;                    // 1 i
    float* F      = Ap;                                      // reuse Ap region after fallback

    k_norm<<<4 * NTOK / 4 / 256, 256, 0, stream>>>(x, norms4, count);
    k_pack<<<dim3(TT / 64, CC / 64, BB), 256, 0, stream>>>(x, norms4, Ap, Bp);
    k_sim<<<dim3(NA / 128, NCH, BB), 256, 0, stream>>>(Ap, Bp, Pv1, Pi1, Pv2);
    k_reduce2<<<BB * NA / 256, 256, 0, stream>>>(Pv1, Pi1, Pv2, sel, wl, count);
    k_fallback<<<2048, 512, 0, stream>>>(Ap, Bp, wl, count, sel);
    k_fuse<<<dim3(CC, BB), 256, 0, stream>>>(x, sel, fw, F);
    k_conv<<<dim3(NA / 64, OC / 64, BB), 256, 0, stream>>>(F, conv_w, gamma, beta, mean, var, out);
}

// Round 19
// 282.506 us; speedup vs baseline: 1.1460x; 1.0503x over previous
//
#include <hip/hip_runtime.h>
#include <math.h>

#define BB 16
#define CC 256
#define TT 4096
#define NA 1024
#define NB 3072
#define OC 512

#define NCH 12         // j-chunks for MFMA sim kernel (256 j each = 2 tiles of 128)
#define NPART (NCH*2)  // partials: chunk x wc-half (race-free direct per-wave writes)
#define DELTA 2e-4f    // margin below which a row falls back to exact fp32 argmax
#define NTOK (BB*TT)   // 65536 tokens

typedef float f32x4 __attribute__((ext_vector_type(4)));
typedef short bf16x8 __attribute__((ext_vector_type(8)));

// ---------------- K1: sum-of-squares partials, float4 over t, C split 4x64 ----------------
__global__ void k_norm(const float* __restrict__ x, float* __restrict__ norms4,
                       int* __restrict__ count) {
    int id = blockIdx.x * 256 + threadIdx.x;    // 65536 threads: chunk x token-quad
    if (id == 0) *count = 0;
    int chunk = id >> 14;                       // 4 c-chunks
    int qid = id & 16383;                       // b*1024 + t4
    int b = qid >> 10;
    int t4 = qid & 1023;
    const float* xp = x + ((size_t)b * CC + chunk * 64) * TT + t4 * 4;
    float4 s = {0.f, 0.f, 0.f, 0.f};
#pragma unroll 16
    for (int c = 0; c < 64; ++c) {
        float4 v = *(const float4*)(xp + (size_t)c * TT);
        s.x = fmaf(v.x, v.x, s.x);
        s.y = fmaf(v.y, v.y, s.y);
        s.z = fmaf(v.z, v.z, s.z);
        s.w = fmaf(v.w, v.w, s.w);
    }
    *(float4*)(norms4 + (size_t)chunk * NTOK + (size_t)qid * 4) = s;
}

// ---------------- K2: transpose-pack normalized a/b tokens (fp32 only) ----------------
__global__ void k_pack(const float* __restrict__ x, const float* __restrict__ norms4,
                       float* __restrict__ Ap, float* __restrict__ Bp) {
    __shared__ float tile[64][65];
    __shared__ float ns[64];
    int b = blockIdx.z, c0 = blockIdx.y * 64, t0 = blockIdx.x * 64;
    int tid = threadIdx.x;
#pragma unroll
    for (int rep = 0; rep < 16; ++rep) {
        int lin = rep * 256 + tid;
        int i = lin >> 6, j = lin & 63;
        tile[i][j] = x[((size_t)b * CC + c0 + i) * TT + t0 + j];
    }
    if (tid < 64) {
        int tok = b * TT + t0 + tid;
        float p = norms4[tok] + norms4[NTOK + tok] + norms4[2 * NTOK + tok] + norms4[3 * NTOK + tok];
        ns[tid] = sqrtf(p);
    }
    __syncthreads();
#pragma unroll
    for (int rep = 0; rep < 16; ++rep) {
        int lin = rep * 256 + tid;
        int j = lin >> 6, i = lin & 63;
        int t = t0 + j;
        float v = tile[i][j] / ns[j];
        if ((t & 3) == 0) {
            Ap[((size_t)b * NA + (t >> 2)) * CC + c0 + i] = v;
        } else {
            int g = t >> 2, r = t & 3;
            Bp[((size_t)b * NB + 3 * g + (r - 1)) * CC + c0 + i] = v;
        }
    }
}

// ---------------- K3: MFMA sim; T14 async-STAGE + T1 XCD-aware block swizzle ----------------
__device__ inline void split8(float4 p0, float4 p1, bf16x8& hi, bf16x8& lo) {
    float f[8] = {p0.x, p0.y, p0.z, p0.w, p1.x, p1.y, p1.z, p1.w};
#pragma unroll
    for (int j = 0; j < 8; ++j) {
        uint u = __float_as_uint(f[j]);
        hi[j] = (short)(u >> 16);
        float hf = __uint_as_float(u & 0xffff0000u);
        lo[j] = (short)(__float_as_uint(f[j] - hf) >> 16);
    }
}

#define LOADT(SRC_BASE, KT, RG)                                                   \
    _Pragma("unroll")                                                             \
    for (int rep = 0; rep < 4; ++rep) {                                           \
        int lin = rep * 256 + tid;                                                \
        int r = lin >> 3, g = lin & 7;                                            \
        const float* sp = (SRC_BASE) + (size_t)r * CC + (KT) * 64 + g * 8;        \
        RG[rep][0] = *(const float4*)sp;                                          \
        RG[rep][1] = *(const float4*)(sp + 4);                                    \
    }

#define WRITET(RG, DH, DL)                                                        \
    _Pragma("unroll")                                                             \
    for (int rep = 0; rep < 4; ++rep) {                                           \
        int lin = rep * 256 + tid;                                                \
        int r = lin >> 3, g = lin & 7;                                            \
        bf16x8 h8, l8;                                                            \
        split8(RG[rep][0], RG[rep][1], h8, l8);                                   \
        int off = r * 128 + ((g ^ (r & 7)) << 4);                                 \
        *(bf16x8*)((DH) + off) = h8;                                              \
        *(bf16x8*)((DL) + off) = l8;                                              \
    }

#define MFMA_TILE(ACC)                                                            \
    _Pragma("unroll")                                                             \
    for (int ks = 0; ks < 2; ++ks) {                                              \
        bf16x8 ahi[4], alo[4];                                                    \
        _Pragma("unroll")                                                         \
        for (int mf = 0; mf < 4; ++mf) {                                          \
            int ra = wr * 64 + mf * 16 + lr;                                      \
            int offa = ra * 128 + (((ks * 4 + lk) ^ (ra & 7)) << 4);              \
            ahi[mf] = *(const bf16x8*)(Ah + offa);                                \
            alo[mf] = *(const bf16x8*)(Al + offa);                                \
        }                                                                         \
        _Pragma("unroll")                                                         \
        for (int nf = 0; nf < 4; ++nf) {                                          \
            int rb = wc * 64 + nf * 16 + lr;                                      \
            int offb = rb * 128 + (((ks * 4 + lk) ^ (rb & 7)) << 4);              \
            bf16x8 bhi = *(const bf16x8*)(Bh + offb);                             \
            bf16x8 blo = *(const bf16x8*)(Bl + offb);                             \
            _Pragma("unroll")                                                     \
            for (int mf = 0; mf < 4; ++mf) {                                      \
                ACC[mf][nf] = __builtin_amdgcn_mfma_f32_16x16x32_bf16(ahi[mf], blo, ACC[mf][nf], 0, 0, 0); \
                ACC[mf][nf] = __builtin_amdgcn_mfma_f32_16x16x32_bf16(alo[mf], bhi, ACC[mf][nf], 0, 0, 0); \
                ACC[mf][nf] = __builtin_amdgcn_mfma_f32_16x16x32_bf16(ahi[mf], bhi, ACC[mf][nf], 0, 0, 0); \
            }                                                                     \
        }                                                                         \
    }

// per-row top2 over one 128-col tile; D mapping col=lane&15, row=(lane>>4)*4+reg [m89]
#define TOP2(ACC, JBASE)                                                          \
    _Pragma("unroll")                                                             \
    for (int mf = 0; mf < 4; ++mf)                                                \
    _Pragma("unroll")                                                             \
        for (int reg = 0; reg < 4; ++reg) {                                       \
            int q = mf * 4 + reg;                                                 \
            float v1 = ACC[mf][0][reg];                                           \
            int i1 = (JBASE) + wc * 64 + lr;                                      \
            float v2 = -1e30f;                                                    \
            _Pragma("unroll")                                                     \
            for (int nf = 1; nf < 4; ++nf) {                                      \
                float xv = ACC[mf][nf][reg];                                      \
                int xi = (JBASE) + wc * 64 + nf * 16 + lr;                        \
                if (xv > v1) { v2 = v1; v1 = xv; i1 = xi; }                       \
                else v2 = fmaxf(v2, xv);                                          \
            }                                                                     \
            _Pragma("unroll")                                                     \
            for (int d = 1; d < 16; d <<= 1) {                                    \
                float ov1 = __shfl_xor(v1, d, 64);                                \
                int oi1 = __shfl_xor(i1, d, 64);                                  \
                float ov2 = __shfl_xor(v2, d, 64);                                \
                bool take = (ov1 > v1) || (ov1 == v1 && oi1 < i1);                \
                float bw = take ? v1 : ov1;                                       \
                v2 = fmaxf(fmaxf(v2, ov2), bw);                                   \
                if (take) { v1 = ov1; i1 = oi1; }                                 \
            }                                                                     \
            bool t2 = (v1 > rv1[q]);                                              \
            float bw2 = t2 ? rv1[q] : v1;                                         \
            rv2[q] = fmaxf(fmaxf(rv2[q], v2), bw2);                               \
            if (t2) { rv1[q] = v1; ri1[q] = i1; }                                 \
        }

__global__ void __launch_bounds__(256, 2) k_sim(const float* __restrict__ Ap,
                                                const float* __restrict__ Bp,
                                                float* __restrict__ Pv1, int* __restrict__ Pi1,
                                                float* __restrict__ Pv2) {
    __shared__ __align__(16) char lds[65536];   // Ah|Al|Bh|Bl, 16KB each ([128][64] bf16 swizzled)
    char* Ah = lds;
    char* Al = lds + 16384;
    char* Bh = lds + 32768;
    char* Bl = lds + 49152;
    // T1: XCD-aware bijective swizzle of the 1536-block 1D grid (1536 % 8 == 0).
    // XCD k gets flat%8==k -> contiguous swz range of 192 blocks = 2 full batches;
    // 8 consecutive swz share one B-chunk + one batch's Ap (~4.25MB ~= one L2).
    const int flat = blockIdx.x;
    const int swz = (flat & 7) * 192 + (flat >> 3);
    const int bx = swz & 7;                     // i-tile (8)
    const int rest = swz >> 3;
    const int ch = rest % NCH;                  // j-chunk (12)
    const int b = rest / NCH;                   // batch (16)
    const int i0 = bx * 128;
    const int tid = threadIdx.x;
    const int l = tid & 63, wid = tid >> 6;
    const int wr = wid >> 1, wc = wid & 1;      // 2x2 wave grid, 64x64 per wave per tile
    const int lr = l & 15, lk = l >> 4;
    const float* Abase = Ap + ((size_t)b * NA + i0) * CC;
    const float* Bbase = Bp + (size_t)b * NB * CC;
    const int j0c = ch * 256;

    float rv1[16], rv2[16];
    int ri1[16];
#pragma unroll
    for (int q = 0; q < 16; ++q) { rv1[q] = -1e30f; rv2[q] = -1e30f; ri1[q] = 0; }

    f32x4 acc0[4][4], acc1[4][4];
#pragma unroll
    for (int mf = 0; mf < 4; ++mf)
#pragma unroll
        for (int nf = 0; nf < 4; ++nf) {
            acc0[mf][nf] = (f32x4){0.f, 0.f, 0.f, 0.f};
            acc1[mf][nf] = (f32x4){0.f, 0.f, 0.f, 0.f};
        }

    float4 rA[4][2], rB[4][2];
    LOADT(Abase, 0, rA)
    LOADT(Bbase + (size_t)j0c * CC, 0, rB)

    for (int kt = 0; kt < 4; ++kt) {
        __syncthreads();                      // prior tile reads done
        WRITET(rA, Ah, Al)                    // split+write prefetched A,B1
        WRITET(rB, Bh, Bl)
        __syncthreads();
        LOADT(Bbase + (size_t)(j0c + 128) * CC, kt, rB)   // issue B2 loads under MFMA0
        MFMA_TILE(acc0)
        __syncthreads();                      // MFMA0 done reading Bh/Bl
        WRITET(rB, Bh, Bl)
        __syncthreads();
        if (kt < 3) {                         // issue next-kt A,B1 loads under MFMA1
            LOADT(Abase, kt + 1, rA)
            LOADT(Bbase + (size_t)j0c * CC, kt + 1, rB)
        }
        MFMA_TILE(acc1)
    }

    TOP2(acc0, j0c)                           // ascending j: tile0 then tile1
    TOP2(acc1, j0c + 128)

    // race-free: each wave writes its own (chunk, wc-half) partial
    if (lr == 0) {
        int pch = ch * 2 + wc;
#pragma unroll
        for (int mf = 0; mf < 4; ++mf)
#pragma unroll
            for (int reg = 0; reg < 4; ++reg) {
                int row = i0 + wr * 64 + mf * 16 + lk * 4 + reg;
                size_t o = ((size_t)b * NPART + pch) * NA + row;
                int q = mf * 4 + reg;
                Pv1[o] = rv1[q]; Pi1[o] = ri1[q]; Pv2[o] = rv2[q];
            }
    }
}

// ---------------- K3b: merge partials -> sel + compact flagged worklist ----------------
__global__ void k_reduce2(const float* __restrict__ Pv1, const int* __restrict__ Pi1,
                          const float* __restrict__ Pv2, int* __restrict__ sel,
                          int* __restrict__ wl, int* __restrict__ count) {
    int idx = blockIdx.x * 256 + threadIdx.x;   // b*NA + a
    int b = idx >> 10;
    int a = idx & 1023;
    float v1 = -1e30f, v2 = -1e30f;
    int i1 = 0x7fffffff;
#pragma unroll
    for (int pc = 0; pc < NPART; ++pc) {
        size_t o = ((size_t)b * NPART + pc) * NA + a;
        float nv1 = Pv1[o];
        int ni1 = Pi1[o];
        bool take = (nv1 > v1) || (nv1 == v1 && ni1 < i1);
        float bw = take ? v1 : nv1;
        v2 = fmaxf(fmaxf(v2, Pv2[o]), bw);
        if (take) { v1 = nv1; i1 = ni1; }
    }
    int g = i1 / 3, r = i1 - 3 * g;
    sel[idx] = 4 * g + r + 1;
    if (v1 - v2 < DELTA) {
        int p = atomicAdd(count, 1);
        wl[p] = idx;
    }
}

// ---------------- K3c: exact fp32 re-argmax for flagged rows (worklist) ----------------
__global__ void __launch_bounds__(512) k_fallback(const float* __restrict__ Ap,
                                                  const float* __restrict__ Bp,
                                                  const int* __restrict__ wl,
                                                  const int* __restrict__ count,
                                                  int* __restrict__ sel) {
    int n = *count;
    __shared__ float arow[CC];
    __shared__ float wv[8];
    __shared__ int wi[8];
    int tid = threadIdx.x;                // 512 threads = 8 waves
    int l = tid & 63, w = tid >> 6;
    int lg = l & 15, grp = l >> 4;
    for (int it = blockIdx.x; it < n; it += gridDim.x) {
        int row = wl[it];
        int b = row >> 10, a = row & 1023;
        __syncthreads();                  // protect arow/wv reuse across iterations
        if (tid < 64) *(float4*)&arow[tid * 4] = *(const float4*)(Ap + ((size_t)b * NA + a) * CC + tid * 4);
        __syncthreads();
        float4 av[4];
#pragma unroll
        for (int q = 0; q < 4; ++q) av[q] = *(const float4*)&arow[q * 64 + lg * 4];
        const float* Bb = Bp + (size_t)b * NB * CC;
        float bv = -1e30f;
        int bi = 0;
        for (int j = w * 4 + grp; j < NB; j += 32) {
            const float* br = Bb + (size_t)j * CC + lg * 4;
            float s = 0.f;
#pragma unroll
            for (int q = 0; q < 4; ++q) {
                float4 bb = *(const float4*)(br + q * 64);
                s = fmaf(av[q].w, bb.w, fmaf(av[q].z, bb.z, fmaf(av[q].y, bb.y, fmaf(av[q].x, bb.x, s))));
            }
#pragma unroll
            for (int d = 1; d < 16; d <<= 1) s += __shfl_xor(s, d, 64);
            if (lg == 0 && s > bv) { bv = s; bi = j; }   // ascending per group-lead
        }
#pragma unroll
        for (int d = 16; d < 64; d <<= 1) {
            float ov = __shfl_xor(bv, d, 64);
            int oi = __shfl_xor(bi, d, 64);
            if (ov > bv || (ov == bv && oi < bi)) { bv = ov; bi = oi; }
        }
        if (l == 0) { wv[w] = bv; wi[w] = bi; }
        __syncthreads();
        if (tid == 0) {
            float vm = wv[0]; int im = wi[0];
#pragma unroll
            for (int q = 1; q < 8; ++q)
                if (wv[q] > vm || (wv[q] == vm && wi[q] < im)) { vm = wv[q]; im = wi[q]; }
            int g = im / 3, r = im - 3 * g;
            sel[row] = 4 * g + r + 1;
        }
    }
}

// ---------------- K4a: fuse; one block per (b,c), x-row staged in LDS ----------------
__global__ void k_fuse(const float* __restrict__ x, const int* __restrict__ sel,
                       const float* __restrict__ fwraw, float* __restrict__ F) {
    __shared__ float row[TT];
    int b = blockIdx.y, c = blockIdx.x;
    int tid = threadIdx.x;
    const float* xr = x + ((size_t)b * CC + c) * TT;
#pragma unroll
    for (int r = 0; r < 4; ++r)
        *(float4*)&row[r * 1024 + tid * 4] = *(const float4*)(xr + r * 1024 + tid * 4);
    float w0 = fminf(fmaxf(fwraw[0], 0.f), 6.f);
    float w1 = fminf(fmaxf(fwraw[1], 0.f), 6.f);
    float s = w0 + w1 + 1e-8f;
    float fw0 = w0 / s, fw1 = w1 / s;
    __syncthreads();
    float4 outv;
    float* op = &outv.x;
#pragma unroll
    for (int u = 0; u < 4; ++u) {
        int p = tid * 4 + u;
        int lin = 4 * p;
        int spa = ((lin & 63) == 0) ? lin + 1 : lin - 1;
        int ssim = sel[b * NA + p];
        float xa = row[lin], xs = row[ssim], xp = row[spa];
        float ms = (xa + xs) * 0.5f;
        float mp = (xa + xp) * 0.5f;
        op[u] = fw0 * ms + fw1 * mp;
    }
    *(float4*)(F + ((size_t)b * CC + c) * NA + tid * 4) = outv;
}

// ---------------- K4b: 1x1 conv GEMM + BN + SiLU ----------------
__global__ void __launch_bounds__(256) k_conv(const float* __restrict__ F, const float* __restrict__ W,
                                              const float* __restrict__ gamma, const float* __restrict__ beta,
                                              const float* __restrict__ mean, const float* __restrict__ var,
                                              float* __restrict__ out) {
    __shared__ float Ws[16][68];
    __shared__ float Fs[16][68];
    int b = blockIdx.z;
    int o0 = blockIdx.y * 64;
    int p0 = blockIdx.x * 64;
    int tid = threadIdx.x;
    int tr = tid >> 4, tc = tid & 15;
    int sr = tid >> 2, skb = (tid & 3) * 4;
    int fkk = tid >> 4, fj = (tid & 15) * 4;
    const float* Fb = F + (size_t)b * CC * NA;
    float acc[4][4];
#pragma unroll
    for (int u = 0; u < 4; ++u)
#pragma unroll
        for (int v = 0; v < 4; ++v) acc[u][v] = 0.f;

    for (int kt = 0; kt < CC / 16; ++kt) {
        __syncthreads();
        float4 w4 = *(const float4*)(W + (size_t)(o0 + sr) * CC + kt * 16 + skb);
        Ws[skb + 0][sr] = w4.x; Ws[skb + 1][sr] = w4.y;
        Ws[skb + 2][sr] = w4.z; Ws[skb + 3][sr] = w4.w;
        float4 f4 = *(const float4*)(Fb + (size_t)(kt * 16 + fkk) * NA + p0 + fj);
        *(float4*)&Fs[fkk][fj] = f4;
        __syncthreads();
#pragma unroll
        for (int kk = 0; kk < 16; ++kk) {
            float4 av = *(const float4*)&Ws[kk][tr * 4];
            float4 bv4 = *(const float4*)&Fs[kk][tc * 4];
            float a_[4] = {av.x, av.y, av.z, av.w};
            float b_[4] = {bv4.x, bv4.y, bv4.z, bv4.w};
#pragma unroll
            for (int u = 0; u < 4; ++u)
#pragma unroll
                for (int v = 0; v < 4; ++v)
                    acc[u][v] = fmaf(a_[u], b_[v], acc[u][v]);
        }
    }
#pragma unroll
    for (int u = 0; u < 4; ++u) {
        int o = o0 + tr * 4 + u;
        float sc = gamma[o] / sqrtf(var[o] + 1e-5f);
        float sh = fmaf(-mean[o], sc, beta[o]);
        float4 r;
        float* rp = &r.x;
#pragma unroll
        for (int v = 0; v < 4; ++v) {
            float y = fmaf(acc[u][v], sc, sh);
            rp[v] = y / (1.f + expf(-y));
        }
        *(float4*)(out + ((size_t)b * OC + o) * NA + p0 + tc * 4) = r;
    }
}

extern "C" void kernel_launch(void* const* d_in, const int* in_sizes, int n_in,
                              void* d_out, int out_size, void* d_ws, size_t ws_size,
                              hipStream_t stream) {
    const float* x      = (const float*)d_in[0];
    const float* conv_w = (const float*)d_in[1];
    const float* gamma  = (const float*)d_in[2];
    const float* beta   = (const float*)d_in[3];
    const float* mean   = (const float*)d_in[4];
    const float* var    = (const float*)d_in[5];
    const float* fw     = (const float*)d_in[6];
    float* out = (float*)d_out;

    float* ws     = (float*)d_ws;
    float* norms4 = ws;                                      // 4*NTOK f
    float* Ap     = norms4 + (size_t)4 * NTOK;               // BB*NA*CC f
    float* Bp     = Ap + (size_t)BB * NA * CC;               // BB*NB*CC f
    float* Pv1    = Bp + (size_t)BB * NB * CC;               // BB*NPART*NA f
    float* Pv2    = Pv1 + (size_t)BB * NPART * NA;           // BB*NPART*NA f
    int*   Pi1    = (int*)(Pv2 + (size_t)BB * NPART * NA);   // BB*NPART*NA i
    int*   sel    = Pi1 + (size_t)BB * NPART * NA;           // BB*NA i
    int*   wl     = sel + (size_t)BB * NA;                   // BB*NA i
    int*   count  = wl + (size_t)BB * NA;                    // 1 i
    float* F      = Ap;                                      // reuse Ap region after fallback

    k_norm<<<NTOK / 256, 256, 0, stream>>>(x, norms4, count);
    k_pack<<<dim3(TT / 64, CC / 64, BB), 256, 0, stream>>>(x, norms4, Ap, Bp);
    k_sim<<<8 * NCH * BB, 256, 0, stream>>>(Ap, Bp, Pv1, Pi1, Pv2);
    k_reduce2<<<BB * NA / 256, 256, 0, stream>>>(Pv1, Pi1, Pv2, sel, wl, count);
    k_fallback<<<2048, 512, 0, stream>>>(Ap, Bp, wl, count, sel);
    k_fuse<<<dim3(CC, BB), 256, 0, stream>>>(x, sel, fw, F);
    k_conv<<<dim3(NA / 64, OC / 64, BB), 256, 0, stream>>>(F, conv_w, gamma, beta, mean, var, out);
}

// Round 20
// 261.723 us; speedup vs baseline: 1.2370x; 1.0794x over previous
//
#include <hip/hip_runtime.h>
#include <math.h>

#define BB 16
#define CC 256
#define TT 4096
#define NA 1024
#define NB 3072
#define OC 512

#define NCH 12         // j-chunks for MFMA sim kernel (256 j each = 2 tiles of 128)
#define NPART (NCH*2)  // partials: chunk x wc-half (race-free direct per-wave writes)
#define DELTA 2e-4f    // margin below which a row falls back to exact fp32 argmax
#define NTOK (BB*TT)   // 65536 tokens

typedef float f32x4 __attribute__((ext_vector_type(4)));
typedef short bf16x8 __attribute__((ext_vector_type(8)));

// ---------------- K1: sum-of-squares partials, float4 over t, C split 4x64 ----------------
__global__ void k_norm(const float* __restrict__ x, float* __restrict__ norms4,
                       int* __restrict__ count) {
    int id = blockIdx.x * 256 + threadIdx.x;    // 65536 threads: chunk x token-quad
    if (id == 0) *count = 0;
    int chunk = id >> 14;                       // 4 c-chunks
    int qid = id & 16383;                       // b*1024 + t4
    int b = qid >> 10;
    int t4 = qid & 1023;
    const float* xp = x + ((size_t)b * CC + chunk * 64) * TT + t4 * 4;
    float4 s = {0.f, 0.f, 0.f, 0.f};
#pragma unroll 16
    for (int c = 0; c < 64; ++c) {
        float4 v = *(const float4*)(xp + (size_t)c * TT);
        s.x = fmaf(v.x, v.x, s.x);
        s.y = fmaf(v.y, v.y, s.y);
        s.z = fmaf(v.z, v.z, s.z);
        s.w = fmaf(v.w, v.w, s.w);
    }
    *(float4*)(norms4 + (size_t)chunk * NTOK + (size_t)qid * 4) = s;
}

// ---------------- K2: transpose-pack normalized a/b tokens (fp32 only) ----------------
__global__ void k_pack(const float* __restrict__ x, const float* __restrict__ norms4,
                       float* __restrict__ Ap, float* __restrict__ Bp) {
    __shared__ float tile[64][65];
    __shared__ float ns[64];
    int b = blockIdx.z, c0 = blockIdx.y * 64, t0 = blockIdx.x * 64;
    int tid = threadIdx.x;
#pragma unroll
    for (int rep = 0; rep < 16; ++rep) {
        int lin = rep * 256 + tid;
        int i = lin >> 6, j = lin & 63;
        tile[i][j] = x[((size_t)b * CC + c0 + i) * TT + t0 + j];
    }
    if (tid < 64) {
        int tok = b * TT + t0 + tid;
        float p = norms4[tok] + norms4[NTOK + tok] + norms4[2 * NTOK + tok] + norms4[3 * NTOK + tok];
        ns[tid] = sqrtf(p);
    }
    __syncthreads();
#pragma unroll
    for (int rep = 0; rep < 16; ++rep) {
        int lin = rep * 256 + tid;
        int j = lin >> 6, i = lin & 63;
        int t = t0 + j;
        float v = tile[i][j] / ns[j];
        if ((t & 3) == 0) {
            Ap[((size_t)b * NA + (t >> 2)) * CC + c0 + i] = v;
        } else {
            int g = t >> 2, r = t & 3;
            Bp[((size_t)b * NB + 3 * g + (r - 1)) * CC + c0 + i] = v;
        }
    }
}

// ---------------- K3: MFMA sim; T14 async-STAGE + T1 XCD-aware block swizzle ----------------
__device__ inline void split8(float4 p0, float4 p1, bf16x8& hi, bf16x8& lo) {
    float f[8] = {p0.x, p0.y, p0.z, p0.w, p1.x, p1.y, p1.z, p1.w};
#pragma unroll
    for (int j = 0; j < 8; ++j) {
        uint u = __float_as_uint(f[j]);
        hi[j] = (short)(u >> 16);
        float hf = __uint_as_float(u & 0xffff0000u);
        lo[j] = (short)(__float_as_uint(f[j] - hf) >> 16);
    }
}

#define LOADT(SRC_BASE, KT, RG)                                                   \
    _Pragma("unroll")                                                             \
    for (int rep = 0; rep < 4; ++rep) {                                           \
        int lin = rep * 256 + tid;                                                \
        int r = lin >> 3, g = lin & 7;                                            \
        const float* sp = (SRC_BASE) + (size_t)r * CC + (KT) * 64 + g * 8;        \
        RG[rep][0] = *(const float4*)sp;                                          \
        RG[rep][1] = *(const float4*)(sp + 4);                                    \
    }

#define WRITET(RG, DH, DL)                                                        \
    _Pragma("unroll")                                                             \
    for (int rep = 0; rep < 4; ++rep) {                                           \
        int lin = rep * 256 + tid;                                                \
        int r = lin >> 3, g = lin & 7;                                            \
        bf16x8 h8, l8;                                                            \
        split8(RG[rep][0], RG[rep][1], h8, l8);                                   \
        int off = r * 128 + ((g ^ (r & 7)) << 4);                                 \
        *(bf16x8*)((DH) + off) = h8;                                              \
        *(bf16x8*)((DL) + off) = l8;                                              \
    }

#define MFMA_TILE(ACC)                                                            \
    _Pragma("unroll")                                                             \
    for (int ks = 0; ks < 2; ++ks) {                                              \
        bf16x8 ahi[4], alo[4];                                                    \
        _Pragma("unroll")                                                         \
        for (int mf = 0; mf < 4; ++mf) {                                          \
            int ra = wr * 64 + mf * 16 + lr;                                      \
            int offa = ra * 128 + (((ks * 4 + lk) ^ (ra & 7)) << 4);              \
            ahi[mf] = *(const bf16x8*)(Ah + offa);                                \
            alo[mf] = *(const bf16x8*)(Al + offa);                                \
        }                                                                         \
        _Pragma("unroll")                                                         \
        for (int nf = 0; nf < 4; ++nf) {                                          \
            int rb = wc * 64 + nf * 16 + lr;                                      \
            int offb = rb * 128 + (((ks * 4 + lk) ^ (rb & 7)) << 4);              \
            bf16x8 bhi = *(const bf16x8*)(Bh + offb);                             \
            bf16x8 blo = *(const bf16x8*)(Bl + offb);                             \
            _Pragma("unroll")                                                     \
            for (int mf = 0; mf < 4; ++mf) {                                      \
                ACC[mf][nf] = __builtin_amdgcn_mfma_f32_16x16x32_bf16(ahi[mf], blo, ACC[mf][nf], 0, 0, 0); \
                ACC[mf][nf] = __builtin_amdgcn_mfma_f32_16x16x32_bf16(alo[mf], bhi, ACC[mf][nf], 0, 0, 0); \
                ACC[mf][nf] = __builtin_amdgcn_mfma_f32_16x16x32_bf16(ahi[mf], bhi, ACC[mf][nf], 0, 0, 0); \
            }                                                                     \
        }                                                                         \
    }

// per-row top2 over one 128-col tile; D mapping col=lane&15, row=(lane>>4)*4+reg [m89]
#define TOP2(ACC, JBASE)                                                          \
    _Pragma("unroll")                                                             \
    for (int mf = 0; mf < 4; ++mf)                                                \
    _Pragma("unroll")                                                             \
        for (int reg = 0; reg < 4; ++reg) {                                       \
            int q = mf * 4 + reg;                                                 \
            float v1 = ACC[mf][0][reg];                                           \
            int i1 = (JBASE) + wc * 64 + lr;                                      \
            float v2 = -1e30f;                                                    \
            _Pragma("unroll")                                                     \
            for (int nf = 1; nf < 4; ++nf) {                                      \
                float xv = ACC[mf][nf][reg];                                      \
                int xi = (JBASE) + wc * 64 + nf * 16 + lr;                        \
                if (xv > v1) { v2 = v1; v1 = xv; i1 = xi; }                       \
                else v2 = fmaxf(v2, xv);                                          \
            }                                                                     \
            _Pragma("unroll")                                                     \
            for (int d = 1; d < 16; d <<= 1) {                                    \
                float ov1 = __shfl_xor(v1, d, 64);                                \
                int oi1 = __shfl_xor(i1, d, 64);                                  \
                float ov2 = __shfl_xor(v2, d, 64);                                \
                bool take = (ov1 > v1) || (ov1 == v1 && oi1 < i1);                \
                float bw = take ? v1 : ov1;                                       \
                v2 = fmaxf(fmaxf(v2, ov2), bw);                                   \
                if (take) { v1 = ov1; i1 = oi1; }                                 \
            }                                                                     \
            bool t2 = (v1 > rv1[q]);                                              \
            float bw2 = t2 ? rv1[q] : v1;                                         \
            rv2[q] = fmaxf(fmaxf(rv2[q], v2), bw2);                               \
            if (t2) { rv1[q] = v1; ri1[q] = i1; }                                 \
        }

__global__ void __launch_bounds__(256, 2) k_sim(const float* __restrict__ Ap,
                                                const float* __restrict__ Bp,
                                                float* __restrict__ Pv1, int* __restrict__ Pi1,
                                                float* __restrict__ Pv2) {
    __shared__ __align__(16) char lds[65536];   // Ah|Al|Bh|Bl, 16KB each ([128][64] bf16 swizzled)
    char* Ah = lds;
    char* Al = lds + 16384;
    char* Bh = lds + 32768;
    char* Bl = lds + 49152;
    // T1: XCD-aware bijective swizzle of the 1536-block 1D grid (1536 % 8 == 0).
    const int flat = blockIdx.x;
    const int swz = (flat & 7) * 192 + (flat >> 3);
    const int bx = swz & 7;                     // i-tile (8)
    const int rest = swz >> 3;
    const int ch = rest % NCH;                  // j-chunk (12)
    const int b = rest / NCH;                   // batch (16)
    const int i0 = bx * 128;
    const int tid = threadIdx.x;
    const int l = tid & 63, wid = tid >> 6;
    const int wr = wid >> 1, wc = wid & 1;      // 2x2 wave grid, 64x64 per wave per tile
    const int lr = l & 15, lk = l >> 4;
    const float* Abase = Ap + ((size_t)b * NA + i0) * CC;
    const float* Bbase = Bp + (size_t)b * NB * CC;
    const int j0c = ch * 256;

    float rv1[16], rv2[16];
    int ri1[16];
#pragma unroll
    for (int q = 0; q < 16; ++q) { rv1[q] = -1e30f; rv2[q] = -1e30f; ri1[q] = 0; }

    f32x4 acc0[4][4], acc1[4][4];
#pragma unroll
    for (int mf = 0; mf < 4; ++mf)
#pragma unroll
        for (int nf = 0; nf < 4; ++nf) {
            acc0[mf][nf] = (f32x4){0.f, 0.f, 0.f, 0.f};
            acc1[mf][nf] = (f32x4){0.f, 0.f, 0.f, 0.f};
        }

    float4 rA[4][2], rB[4][2];
    LOADT(Abase, 0, rA)
    LOADT(Bbase + (size_t)j0c * CC, 0, rB)

    for (int kt = 0; kt < 4; ++kt) {
        __syncthreads();                      // prior tile reads done
        WRITET(rA, Ah, Al)                    // split+write prefetched A,B1
        WRITET(rB, Bh, Bl)
        __syncthreads();
        LOADT(Bbase + (size_t)(j0c + 128) * CC, kt, rB)   // issue B2 loads under MFMA0
        MFMA_TILE(acc0)
        __syncthreads();                      // MFMA0 done reading Bh/Bl
        WRITET(rB, Bh, Bl)
        __syncthreads();
        if (kt < 3) {                         // issue next-kt A,B1 loads under MFMA1
            LOADT(Abase, kt + 1, rA)
            LOADT(Bbase + (size_t)j0c * CC, kt + 1, rB)
        }
        MFMA_TILE(acc1)
    }

    TOP2(acc0, j0c)                           // ascending j: tile0 then tile1
    TOP2(acc1, j0c + 128)

    // race-free: each wave writes its own (chunk, wc-half) partial
    if (lr == 0) {
        int pch = ch * 2 + wc;
#pragma unroll
        for (int mf = 0; mf < 4; ++mf)
#pragma unroll
            for (int reg = 0; reg < 4; ++reg) {
                int row = i0 + wr * 64 + mf * 16 + lk * 4 + reg;
                size_t o = ((size_t)b * NPART + pch) * NA + row;
                int q = mf * 4 + reg;
                Pv1[o] = rv1[q]; Pi1[o] = ri1[q]; Pv2[o] = rv2[q];
            }
    }
}

// ---------------- K3b: merge partials -> sel + compact flagged worklist ----------------
__global__ void k_reduce2(const float* __restrict__ Pv1, const int* __restrict__ Pi1,
                          const float* __restrict__ Pv2, int* __restrict__ sel,
                          int* __restrict__ wl, int* __restrict__ count) {
    int idx = blockIdx.x * 256 + threadIdx.x;   // b*NA + a
    int b = idx >> 10;
    int a = idx & 1023;
    float v1 = -1e30f, v2 = -1e30f;
    int i1 = 0x7fffffff;
#pragma unroll
    for (int pc = 0; pc < NPART; ++pc) {
        size_t o = ((size_t)b * NPART + pc) * NA + a;
        float nv1 = Pv1[o];
        int ni1 = Pi1[o];
        bool take = (nv1 > v1) || (nv1 == v1 && ni1 < i1);
        float bw = take ? v1 : nv1;
        v2 = fmaxf(fmaxf(v2, Pv2[o]), bw);
        if (take) { v1 = nv1; i1 = ni1; }
    }
    int g = i1 / 3, r = i1 - 3 * g;
    sel[idx] = 4 * g + r + 1;
    if (v1 - v2 < DELTA) {
        int p = atomicAdd(count, 1);
        wl[p] = idx;
    }
}

// ---------------- K3c: exact fp32 re-argmax for flagged rows (worklist) ----------------
__global__ void __launch_bounds__(512) k_fallback(const float* __restrict__ Ap,
                                                  const float* __restrict__ Bp,
                                                  const int* __restrict__ wl,
                                                  const int* __restrict__ count,
                                                  int* __restrict__ sel) {
    int n = *count;
    __shared__ float arow[CC];
    __shared__ float wv[8];
    __shared__ int wi[8];
    int tid = threadIdx.x;                // 512 threads = 8 waves
    int l = tid & 63, w = tid >> 6;
    int lg = l & 15, grp = l >> 4;
    for (int it = blockIdx.x; it < n; it += gridDim.x) {
        int row = wl[it];
        int b = row >> 10, a = row & 1023;
        __syncthreads();                  // protect arow/wv reuse across iterations
        if (tid < 64) *(float4*)&arow[tid * 4] = *(const float4*)(Ap + ((size_t)b * NA + a) * CC + tid * 4);
        __syncthreads();
        float4 av[4];
#pragma unroll
        for (int q = 0; q < 4; ++q) av[q] = *(const float4*)&arow[q * 64 + lg * 4];
        const float* Bb = Bp + (size_t)b * NB * CC;
        float bv = -1e30f;
        int bi = 0;
        for (int j = w * 4 + grp; j < NB; j += 32) {
            const float* br = Bb + (size_t)j * CC + lg * 4;
            float s = 0.f;
#pragma unroll
            for (int q = 0; q < 4; ++q) {
                float4 bb = *(const float4*)(br + q * 64);
                s = fmaf(av[q].w, bb.w, fmaf(av[q].z, bb.z, fmaf(av[q].y, bb.y, fmaf(av[q].x, bb.x, s))));
            }
#pragma unroll
            for (int d = 1; d < 16; d <<= 1) s += __shfl_xor(s, d, 64);
            if (lg == 0 && s > bv) { bv = s; bi = j; }   // ascending per group-lead
        }
#pragma unroll
        for (int d = 16; d < 64; d <<= 1) {
            float ov = __shfl_xor(bv, d, 64);
            int oi = __shfl_xor(bi, d, 64);
            if (ov > bv || (ov == bv && oi < bi)) { bv = ov; bi = oi; }
        }
        if (l == 0) { wv[w] = bv; wi[w] = bi; }
        __syncthreads();
        if (tid == 0) {
            float vm = wv[0]; int im = wi[0];
#pragma unroll
            for (int q = 1; q < 8; ++q)
                if (wv[q] > vm || (wv[q] == vm && wi[q] < im)) { vm = wv[q]; im = wi[q]; }
            int g = im / 3, r = im - 3 * g;
            sel[row] = 4 * g + r + 1;
        }
    }
}

// ---------------- K4a: fuse; one block per (b,c), x-row staged in LDS ----------------
__global__ void k_fuse(const float* __restrict__ x, const int* __restrict__ sel,
                       const float* __restrict__ fwraw, float* __restrict__ F) {
    __shared__ float row[TT];
    int b = blockIdx.y, c = blockIdx.x;
    int tid = threadIdx.x;
    const float* xr = x + ((size_t)b * CC + c) * TT;
#pragma unroll
    for (int r = 0; r < 4; ++r)
        *(float4*)&row[r * 1024 + tid * 4] = *(const float4*)(xr + r * 1024 + tid * 4);
    float w0 = fminf(fmaxf(fwraw[0], 0.f), 6.f);
    float w1 = fminf(fmaxf(fwraw[1], 0.f), 6.f);
    float s = w0 + w1 + 1e-8f;
    float fw0 = w0 / s, fw1 = w1 / s;
    __syncthreads();
    float4 outv;
    float* op = &outv.x;
#pragma unroll
    for (int u = 0; u < 4; ++u) {
        int p = tid * 4 + u;
        int lin = 4 * p;
        int spa = ((lin & 63) == 0) ? lin + 1 : lin - 1;
        int ssim = sel[b * NA + p];
        float xa = row[lin], xs = row[ssim], xp = row[spa];
        float ms = (xa + xs) * 0.5f;
        float mp = (xa + xp) * 0.5f;
        op[u] = fw0 * ms + fw1 * mp;
    }
    *(float4*)(F + ((size_t)b * CC + c) * NA + tid * 4) = outv;
}

// ---------------- K4b: 1x1 conv via MFMA (bf16 hi/lo 3-pass) + BN + SiLU ----------------
// A = W rows (o, k=c contiguous), staged as swizzled bf16 hi/lo [64][64].
// B = F^T fragments read column-wise from fp32 LDS tile [64][129] (+1 pad:
// stride%32==1 -> 2-way bank aliasing max, free per m136), split in-reg.
// D mapping row=o, col=p [m89], same operand convention as verified k_sim.
__global__ void __launch_bounds__(256, 3) k_conv(const float* __restrict__ F, const float* __restrict__ W,
                                                 const float* __restrict__ gamma, const float* __restrict__ beta,
                                                 const float* __restrict__ mean, const float* __restrict__ var,
                                                 float* __restrict__ out) {
    __shared__ __align__(16) char lds[49408];   // Wh 8K | Wl 8K | Ff[64][129] fp32 33024B
    char* Wh = lds;
    char* Wl = lds + 8192;
    float* Ff = (float*)(lds + 16384);
    const int b = blockIdx.z;
    const int o0 = blockIdx.y * 64;
    const int p0 = blockIdx.x * 128;
    const int tid = threadIdx.x;
    const int l = tid & 63, wid = tid >> 6;
    const int wr = wid >> 1, wc = wid & 1;      // wave tile: 32 o x 64 p
    const int lr = l & 15, lk = l >> 4;
    const float* Wbase = W + (size_t)o0 * CC;
    const float* Fb = F + (size_t)b * CC * NA;

    f32x4 acc[2][4];
#pragma unroll
    for (int mf = 0; mf < 2; ++mf)
#pragma unroll
        for (int nf = 0; nf < 4; ++nf) acc[mf][nf] = (f32x4){0.f, 0.f, 0.f, 0.f};

    for (int kt = 0; kt < 4; ++kt) {
        __syncthreads();
        // stage W 64o x 64c -> swizzled bf16 hi/lo
#pragma unroll
        for (int rep = 0; rep < 2; ++rep) {
            int lin = rep * 256 + tid;
            int r = lin >> 3, g = lin & 7;
            const float* sp = Wbase + (size_t)r * CC + kt * 64 + g * 8;
            float4 q0 = *(const float4*)sp;
            float4 q1 = *(const float4*)(sp + 4);
            bf16x8 h8, l8;
            split8(q0, q1, h8, l8);
            int off = r * 128 + ((g ^ (r & 7)) << 4);
            *(bf16x8*)(Wh + off) = h8;
            *(bf16x8*)(Wl + off) = l8;
        }
        // stage F 64c x 128p fp32 (c-major, pad 129), coalesced loads
#pragma unroll
        for (int rep = 0; rep < 8; ++rep) {
            int lin = rep * 256 + tid;
            int c = lin >> 5, i4 = lin & 31;
            float4 fv = *(const float4*)(Fb + (size_t)(kt * 64 + c) * NA + p0 + i4 * 4);
            float* dp = Ff + c * 129 + i4 * 4;
            dp[0] = fv.x; dp[1] = fv.y; dp[2] = fv.z; dp[3] = fv.w;
        }
        __syncthreads();
#pragma unroll
        for (int ks = 0; ks < 2; ++ks) {
            bf16x8 whi[2], wlo[2];
#pragma unroll
            for (int mf = 0; mf < 2; ++mf) {
                int ra = wr * 32 + mf * 16 + lr;
                int offa = ra * 128 + (((ks * 4 + lk) ^ (ra & 7)) << 4);
                whi[mf] = *(const bf16x8*)(Wh + offa);
                wlo[mf] = *(const bf16x8*)(Wl + offa);
            }
#pragma unroll
            for (int nf = 0; nf < 4; ++nf) {
                int rb = wc * 64 + nf * 16 + lr;          // p within tile
                const float* cp = Ff + (ks * 4 + lk) * 8 * 129 + rb;
                bf16x8 bhi, blo;
#pragma unroll
                for (int e = 0; e < 8; ++e) {
                    float fv = cp[e * 129];
                    uint u = __float_as_uint(fv);
                    bhi[e] = (short)(u >> 16);
                    float hf = __uint_as_float(u & 0xffff0000u);
                    blo[e] = (short)(__float_as_uint(fv - hf) >> 16);
                }
#pragma unroll
                for (int mf = 0; mf < 2; ++mf) {
                    acc[mf][nf] = __builtin_amdgcn_mfma_f32_16x16x32_bf16(whi[mf], blo, acc[mf][nf], 0, 0, 0);
                    acc[mf][nf] = __builtin_amdgcn_mfma_f32_16x16x32_bf16(wlo[mf], bhi, acc[mf][nf], 0, 0, 0);
                    acc[mf][nf] = __builtin_amdgcn_mfma_f32_16x16x32_bf16(whi[mf], bhi, acc[mf][nf], 0, 0, 0);
                }
            }
        }
    }
    // epilogue: BN + SiLU; D row=o (lk*4+reg within 16), col=p (lr) [m89]
#pragma unroll
    for (int mf = 0; mf < 2; ++mf)
#pragma unroll
        for (int reg = 0; reg < 4; ++reg) {
            int o = o0 + wr * 32 + mf * 16 + lk * 4 + reg;
            float sc = gamma[o] / sqrtf(var[o] + 1e-5f);
            float sh = fmaf(-mean[o], sc, beta[o]);
#pragma unroll
            for (int nf = 0; nf < 4; ++nf) {
                float y = fmaf(acc[mf][nf][reg], sc, sh);
                out[((size_t)b * OC + o) * NA + p0 + wc * 64 + nf * 16 + lr] = y / (1.f + expf(-y));
            }
        }
}

extern "C" void kernel_launch(void* const* d_in, const int* in_sizes, int n_in,
                              void* d_out, int out_size, void* d_ws, size_t ws_size,
                              hipStream_t stream) {
    const float* x      = (const float*)d_in[0];
    const float* conv_w = (const float*)d_in[1];
    const float* gamma  = (const float*)d_in[2];
    const float* beta   = (const float*)d_in[3];
    const float* mean   = (const float*)d_in[4];
    const float* var    = (const float*)d_in[5];
    const float* fw     = (const float*)d_in[6];
    float* out = (float*)d_out;

    float* ws     = (float*)d_ws;
    float* norms4 = ws;                                      // 4*NTOK f
    float* Ap     = norms4 + (size_t)4 * NTOK;               // BB*NA*CC f
    float* Bp     = Ap + (size_t)BB * NA * CC;               // BB*NB*CC f
    float* Pv1    = Bp + (size_t)BB * NB * CC;               // BB*NPART*NA f
    float* Pv2    = Pv1 + (size_t)BB * NPART * NA;           // BB*NPART*NA f
    int*   Pi1    = (int*)(Pv2 + (size_t)BB * NPART * NA);   // BB*NPART*NA i
    int*   sel    = Pi1 + (size_t)BB * NPART * NA;           // BB*NA i
    int*   wl     = sel + (size_t)BB * NA;                   // BB*NA i
    int*   count  = wl + (size_t)BB * NA;                    // 1 i
    float* F      = Ap;                                      // reuse Ap region after fallback

    k_norm<<<NTOK / 256, 256, 0, stream>>>(x, norms4, count);
    k_pack<<<dim3(TT / 64, CC / 64, BB), 256, 0, stream>>>(x, norms4, Ap, Bp);
    k_sim<<<8 * NCH * BB, 256, 0, stream>>>(Ap, Bp, Pv1, Pi1, Pv2);
    k_reduce2<<<BB * NA / 256, 256, 0, stream>>>(Pv1, Pi1, Pv2, sel, wl, count);
    k_fallback<<<2048, 512, 0, stream>>>(Ap, Bp, wl, count, sel);
    k_fuse<<<dim3(CC, BB), 256, 0, stream>>>(x, sel, fw, F);
    k_conv<<<dim3(NA / 128, OC / 64, BB), 256, 0, stream>>>(F, conv_w, gamma, beta, mean, var, out);
}

// Round 21
// 259.640 us; speedup vs baseline: 1.2469x; 1.0080x over previous
//
#include <hip/hip_runtime.h>
#include <math.h>

#define BB 16
#define CC 256
#define TT 4096
#define NA 1024
#define NB 3072
#define OC 512

#define NCH 12         // j-chunks for MFMA sim kernel (256 j each = 2 tiles of 128)
#define NPART (NCH*2)  // partials: chunk x wc-half (race-free direct per-wave writes)
#define DELTA 2e-4f    // margin below which a row falls back to exact fp32 argmax
#define NTOK (BB*TT)   // 65536 tokens

typedef float f32x4 __attribute__((ext_vector_type(4)));
typedef short bf16x8 __attribute__((ext_vector_type(8)));

// ---------------- K1: sum-of-squares partials, float4 over t, C split 4x64 ----------------
__global__ void k_norm(const float* __restrict__ x, float* __restrict__ norms4,
                       int* __restrict__ count) {
    int id = blockIdx.x * 256 + threadIdx.x;    // 65536 threads: chunk x token-quad
    if (id == 0) *count = 0;
    int chunk = id >> 14;                       // 4 c-chunks
    int qid = id & 16383;                       // b*1024 + t4
    int b = qid >> 10;
    int t4 = qid & 1023;
    const float* xp = x + ((size_t)b * CC + chunk * 64) * TT + t4 * 4;
    float4 s = {0.f, 0.f, 0.f, 0.f};
#pragma unroll 16
    for (int c = 0; c < 64; ++c) {
        float4 v = *(const float4*)(xp + (size_t)c * TT);
        s.x = fmaf(v.x, v.x, s.x);
        s.y = fmaf(v.y, v.y, s.y);
        s.z = fmaf(v.z, v.z, s.z);
        s.w = fmaf(v.w, v.w, s.w);
    }
    *(float4*)(norms4 + (size_t)chunk * NTOK + (size_t)qid * 4) = s;
}

// ---------------- K2: transpose-pack, vectorized both phases (G13) ----------------
// tilT[t][c] pad 68: float4 global loads along t (16B/lane), scalar LDS scatter
// (8-way bank alias tolerated; LDS not binding), float4 LDS reads (byte = 272t+16c,
// 16B-aligned) + float4 coalesced global writes. Per-element division preserved.
__global__ void k_pack(const float* __restrict__ x, const float* __restrict__ norms4,
                       float* __restrict__ Ap, float* __restrict__ Bp) {
    __shared__ float tilT[64][68];
    __shared__ float ns[64];
    int b = blockIdx.z, c0 = blockIdx.y * 64, t0 = blockIdx.x * 64;
    int tid = threadIdx.x;
#pragma unroll
    for (int rep = 0; rep < 4; ++rep) {
        int i = rep * 16 + (tid >> 4);          // c within tile
        int j4 = tid & 15;                      // t-quad
        float4 v = *(const float4*)(x + ((size_t)b * CC + c0 + i) * TT + t0 + j4 * 4);
        tilT[j4 * 4 + 0][i] = v.x;
        tilT[j4 * 4 + 1][i] = v.y;
        tilT[j4 * 4 + 2][i] = v.z;
        tilT[j4 * 4 + 3][i] = v.w;
    }
    if (tid < 64) {
        int tok = b * TT + t0 + tid;
        ns[tid] = sqrtf(norms4[tok] + norms4[NTOK + tok] + norms4[2 * NTOK + tok] + norms4[3 * NTOK + tok]);
    }
    __syncthreads();
#pragma unroll
    for (int rep = 0; rep < 4; ++rep) {
        int lin = rep * 256 + tid;
        int j = lin >> 4, i4 = lin & 15;        // token, c-quad
        float nsj = ns[j];
        float4 o;
        o.x = tilT[j][i4 * 4 + 0] / nsj;
        o.y = tilT[j][i4 * 4 + 1] / nsj;
        o.z = tilT[j][i4 * 4 + 2] / nsj;
        o.w = tilT[j][i4 * 4 + 3] / nsj;
        int t = t0 + j;
        if ((t & 3) == 0) {
            *(float4*)(Ap + ((size_t)b * NA + (t >> 2)) * CC + c0 + i4 * 4) = o;
        } else {
            int g = t >> 2, r = t & 3;
            *(float4*)(Bp + ((size_t)b * NB + 3 * g + (r - 1)) * CC + c0 + i4 * 4) = o;
        }
    }
}

// ---------------- K3: MFMA sim; T14 async-STAGE + T1 XCD-aware block swizzle ----------------
__device__ inline void split8(float4 p0, float4 p1, bf16x8& hi, bf16x8& lo) {
    float f[8] = {p0.x, p0.y, p0.z, p0.w, p1.x, p1.y, p1.z, p1.w};
#pragma unroll
    for (int j = 0; j < 8; ++j) {
        uint u = __float_as_uint(f[j]);
        hi[j] = (short)(u >> 16);
        float hf = __uint_as_float(u & 0xffff0000u);
        lo[j] = (short)(__float_as_uint(f[j] - hf) >> 16);
    }
}

#define LOADT(SRC_BASE, KT, RG)                                                   \
    _Pragma("unroll")                                                             \
    for (int rep = 0; rep < 4; ++rep) {                                           \
        int lin = rep * 256 + tid;                                                \
        int r = lin >> 3, g = lin & 7;                                            \
        const float* sp = (SRC_BASE) + (size_t)r * CC + (KT) * 64 + g * 8;        \
        RG[rep][0] = *(const float4*)sp;                                          \
        RG[rep][1] = *(const float4*)(sp + 4);                                    \
    }

#define WRITET(RG, DH, DL)                                                        \
    _Pragma("unroll")                                                             \
    for (int rep = 0; rep < 4; ++rep) {                                           \
        int lin = rep * 256 + tid;                                                \
        int r = lin >> 3, g = lin & 7;                                            \
        bf16x8 h8, l8;                                                            \
        split8(RG[rep][0], RG[rep][1], h8, l8);                                   \
        int off = r * 128 + ((g ^ (r & 7)) << 4);                                 \
        *(bf16x8*)((DH) + off) = h8;                                              \
        *(bf16x8*)((DL) + off) = l8;                                              \
    }

#define MFMA_TILE(ACC)                                                            \
    _Pragma("unroll")                                                             \
    for (int ks = 0; ks < 2; ++ks) {                                              \
        bf16x8 ahi[4], alo[4];                                                    \
        _Pragma("unroll")                                                         \
        for (int mf = 0; mf < 4; ++mf) {                                          \
            int ra = wr * 64 + mf * 16 + lr;                                      \
            int offa = ra * 128 + (((ks * 4 + lk) ^ (ra & 7)) << 4);              \
            ahi[mf] = *(const bf16x8*)(Ah + offa);                                \
            alo[mf] = *(const bf16x8*)(Al + offa);                                \
        }                                                                         \
        _Pragma("unroll")                                                         \
        for (int nf = 0; nf < 4; ++nf) {                                          \
            int rb = wc * 64 + nf * 16 + lr;                                      \
            int offb = rb * 128 + (((ks * 4 + lk) ^ (rb & 7)) << 4);              \
            bf16x8 bhi = *(const bf16x8*)(Bh + offb);                             \
            bf16x8 blo = *(const bf16x8*)(Bl + offb);                             \
            _Pragma("unroll")                                                     \
            for (int mf = 0; mf < 4; ++mf) {                                      \
                ACC[mf][nf] = __builtin_amdgcn_mfma_f32_16x16x32_bf16(ahi[mf], blo, ACC[mf][nf], 0, 0, 0); \
                ACC[mf][nf] = __builtin_amdgcn_mfma_f32_16x16x32_bf16(alo[mf], bhi, ACC[mf][nf], 0, 0, 0); \
                ACC[mf][nf] = __builtin_amdgcn_mfma_f32_16x16x32_bf16(ahi[mf], bhi, ACC[mf][nf], 0, 0, 0); \
            }                                                                     \
        }                                                                         \
    }

// per-row top2 over one 128-col tile; D mapping col=lane&15, row=(lane>>4)*4+reg [m89]
#define TOP2(ACC, JBASE)                                                          \
    _Pragma("unroll")                                                             \
    for (int mf = 0; mf < 4; ++mf)                                                \
    _Pragma("unroll")                                                             \
        for (int reg = 0; reg < 4; ++reg) {                                       \
            int q = mf * 4 + reg;                                                 \
            float v1 = ACC[mf][0][reg];                                           \
            int i1 = (JBASE) + wc * 64 + lr;                                      \
            float v2 = -1e30f;                                                    \
            _Pragma("unroll")                                                     \
            for (int nf = 1; nf < 4; ++nf) {                                      \
                float xv = ACC[mf][nf][reg];                                      \
                int xi = (JBASE) + wc * 64 + nf * 16 + lr;                        \
                if (xv > v1) { v2 = v1; v1 = xv; i1 = xi; }                       \
                else v2 = fmaxf(v2, xv);                                          \
            }                                                                     \
            _Pragma("unroll")                                                     \
            for (int d = 1; d < 16; d <<= 1) {                                    \
                float ov1 = __shfl_xor(v1, d, 64);                                \
                int oi1 = __shfl_xor(i1, d, 64);                                  \
                float ov2 = __shfl_xor(v2, d, 64);                                \
                bool take = (ov1 > v1) || (ov1 == v1 && oi1 < i1);                \
                float bw = take ? v1 : ov1;                                      \
                v2 = fmaxf(fmaxf(v2, ov2), bw);                                   \
                if (take) { v1 = ov1; i1 = oi1; }                                 \
            }                                                                     \
            bool t2 = (v1 > rv1[q]);                                              \
            float bw2 = t2 ? rv1[q] : v1;                                         \
            rv2[q] = fmaxf(fmaxf(rv2[q], v2), bw2);                               \
            if (t2) { rv1[q] = v1; ri1[q] = i1; }                                 \
        }

__global__ void __launch_bounds__(256, 2) k_sim(const float* __restrict__ Ap,
                                                const float* __restrict__ Bp,
                                                float* __restrict__ Pv1, int* __restrict__ Pi1,
                                                float* __restrict__ Pv2) {
    __shared__ __align__(16) char lds[65536];   // Ah|Al|Bh|Bl, 16KB each ([128][64] bf16 swizzled)
    char* Ah = lds;
    char* Al = lds + 16384;
    char* Bh = lds + 32768;
    char* Bl = lds + 49152;
    // T1: XCD-aware bijective swizzle of the 1536-block 1D grid (1536 % 8 == 0).
    const int flat = blockIdx.x;
    const int swz = (flat & 7) * 192 + (flat >> 3);
    const int bx = swz & 7;                     // i-tile (8)
    const int rest = swz >> 3;
    const int ch = rest % NCH;                  // j-chunk (12)
    const int b = rest / NCH;                   // batch (16)
    const int i0 = bx * 128;
    const int tid = threadIdx.x;
    const int l = tid & 63, wid = tid >> 6;
    const int wr = wid >> 1, wc = wid & 1;      // 2x2 wave grid, 64x64 per wave per tile
    const int lr = l & 15, lk = l >> 4;
    const float* Abase = Ap + ((size_t)b * NA + i0) * CC;
    const float* Bbase = Bp + (size_t)b * NB * CC;
    const int j0c = ch * 256;

    float rv1[16], rv2[16];
    int ri1[16];
#pragma unroll
    for (int q = 0; q < 16; ++q) { rv1[q] = -1e30f; rv2[q] = -1e30f; ri1[q] = 0; }

    f32x4 acc0[4][4], acc1[4][4];
#pragma unroll
    for (int mf = 0; mf < 4; ++mf)
#pragma unroll
        for (int nf = 0; nf < 4; ++nf) {
            acc0[mf][nf] = (f32x4){0.f, 0.f, 0.f, 0.f};
            acc1[mf][nf] = (f32x4){0.f, 0.f, 0.f, 0.f};
        }

    float4 rA[4][2], rB[4][2];
    LOADT(Abase, 0, rA)
    LOADT(Bbase + (size_t)j0c * CC, 0, rB)

    for (int kt = 0; kt < 4; ++kt) {
        __syncthreads();                      // prior tile reads done
        WRITET(rA, Ah, Al)                    // split+write prefetched A,B1
        WRITET(rB, Bh, Bl)
        __syncthreads();
        LOADT(Bbase + (size_t)(j0c + 128) * CC, kt, rB)   // issue B2 loads under MFMA0
        MFMA_TILE(acc0)
        __syncthreads();                      // MFMA0 done reading Bh/Bl
        WRITET(rB, Bh, Bl)
        __syncthreads();
        if (kt < 3) {                         // issue next-kt A,B1 loads under MFMA1
            LOADT(Abase, kt + 1, rA)
            LOADT(Bbase + (size_t)j0c * CC, kt + 1, rB)
        }
        MFMA_TILE(acc1)
    }

    TOP2(acc0, j0c)                           // ascending j: tile0 then tile1
    TOP2(acc1, j0c + 128)

    // race-free: each wave writes its own (chunk, wc-half) partial
    if (lr == 0) {
        int pch = ch * 2 + wc;
#pragma unroll
        for (int mf = 0; mf < 4; ++mf)
#pragma unroll
            for (int reg = 0; reg < 4; ++reg) {
                int row = i0 + wr * 64 + mf * 16 + lk * 4 + reg;
                size_t o = ((size_t)b * NPART + pch) * NA + row;
                int q = mf * 4 + reg;
                Pv1[o] = rv1[q]; Pi1[o] = ri1[q]; Pv2[o] = rv2[q];
            }
    }
}

// ---------------- K3b: merge partials -> sel + compact flagged worklist ----------------
__global__ void k_reduce2(const float* __restrict__ Pv1, const int* __restrict__ Pi1,
                          const float* __restrict__ Pv2, int* __restrict__ sel,
                          int* __restrict__ wl, int* __restrict__ count) {
    int idx = blockIdx.x * 256 + threadIdx.x;   // b*NA + a
    int b = idx >> 10;
    int a = idx & 1023;
    float v1 = -1e30f, v2 = -1e30f;
    int i1 = 0x7fffffff;
#pragma unroll
    for (int pc = 0; pc < NPART; ++pc) {
        size_t o = ((size_t)b * NPART + pc) * NA + a;
        float nv1 = Pv1[o];
        int ni1 = Pi1[o];
        bool take = (nv1 > v1) || (nv1 == v1 && ni1 < i1);
        float bw = take ? v1 : nv1;
        v2 = fmaxf(fmaxf(v2, Pv2[o]), bw);
        if (take) { v1 = nv1; i1 = ni1; }
    }
    int g = i1 / 3, r = i1 - 3 * g;
    sel[idx] = 4 * g + r + 1;
    if (v1 - v2 < DELTA) {
        int p = atomicAdd(count, 1);
        wl[p] = idx;
    }
}

// ---------------- K3c: exact fp32 re-argmax for flagged rows (worklist) ----------------
__global__ void __launch_bounds__(512) k_fallback(const float* __restrict__ Ap,
                                                  const float* __restrict__ Bp,
                                                  const int* __restrict__ wl,
                                                  const int* __restrict__ count,
                                                  int* __restrict__ sel) {
    int n = *count;
    __shared__ float arow[CC];
    __shared__ float wv[8];
    __shared__ int wi[8];
    int tid = threadIdx.x;                // 512 threads = 8 waves
    int l = tid & 63, w = tid >> 6;
    int lg = l & 15, grp = l >> 4;
    for (int it = blockIdx.x; it < n; it += gridDim.x) {
        int row = wl[it];
        int b = row >> 10, a = row & 1023;
        __syncthreads();                  // protect arow/wv reuse across iterations
        if (tid < 64) *(float4*)&arow[tid * 4] = *(const float4*)(Ap + ((size_t)b * NA + a) * CC + tid * 4);
        __syncthreads();
        float4 av[4];
#pragma unroll
        for (int q = 0; q < 4; ++q) av[q] = *(const float4*)&arow[q * 64 + lg * 4];
        const float* Bb = Bp + (size_t)b * NB * CC;
        float bv = -1e30f;
        int bi = 0;
        for (int j = w * 4 + grp; j < NB; j += 32) {
            const float* br = Bb + (size_t)j * CC + lg * 4;
            float s = 0.f;
#pragma unroll
            for (int q = 0; q < 4; ++q) {
                float4 bb = *(const float4*)(br + q * 64);
                s = fmaf(av[q].w, bb.w, fmaf(av[q].z, bb.z, fmaf(av[q].y, bb.y, fmaf(av[q].x, bb.x, s))));
            }
#pragma unroll
            for (int d = 1; d < 16; d <<= 1) s += __shfl_xor(s, d, 64);
            if (lg == 0 && s > bv) { bv = s; bi = j; }   // ascending per group-lead
        }
#pragma unroll
        for (int d = 16; d < 64; d <<= 1) {
            float ov = __shfl_xor(bv, d, 64);
            int oi = __shfl_xor(bi, d, 64);
            if (ov > bv || (ov == bv && oi < bi)) { bv = ov; bi = oi; }
        }
        if (l == 0) { wv[w] = bv; wi[w] = bi; }
        __syncthreads();
        if (tid == 0) {
            float vm = wv[0]; int im = wi[0];
#pragma unroll
            for (int q = 1; q < 8; ++q)
                if (wv[q] > vm || (wv[q] == vm && wi[q] < im)) { vm = wv[q]; im = wi[q]; }
            int g = im / 3, r = im - 3 * g;
            sel[row] = 4 * g + r + 1;
        }
    }
}

// ---------------- K4a: fuse; one block per (b,c), x-row staged in LDS ----------------
__global__ void k_fuse(const float* __restrict__ x, const int* __restrict__ sel,
                       const float* __restrict__ fwraw, float* __restrict__ F) {
    __shared__ float row[TT];
    int b = blockIdx.y, c = blockIdx.x;
    int tid = threadIdx.x;
    const float* xr = x + ((size_t)b * CC + c) * TT;
#pragma unroll
    for (int r = 0; r < 4; ++r)
        *(float4*)&row[r * 1024 + tid * 4] = *(const float4*)(xr + r * 1024 + tid * 4);
    float w0 = fminf(fmaxf(fwraw[0], 0.f), 6.f);
    float w1 = fminf(fmaxf(fwraw[1], 0.f), 6.f);
    float s = w0 + w1 + 1e-8f;
    float fw0 = w0 / s, fw1 = w1 / s;
    __syncthreads();
    float4 outv;
    float* op = &outv.x;
#pragma unroll
    for (int u = 0; u < 4; ++u) {
        int p = tid * 4 + u;
        int lin = 4 * p;
        int spa = ((lin & 63) == 0) ? lin + 1 : lin - 1;
        int ssim = sel[b * NA + p];
        float xa = row[lin], xs = row[ssim], xp = row[spa];
        float ms = (xa + xs) * 0.5f;
        float mp = (xa + xp) * 0.5f;
        op[u] = fw0 * ms + fw1 * mp;
    }
    *(float4*)(F + ((size_t)b * CC + c) * NA + tid * 4) = outv;
}

// ---------------- K4b: 1x1 conv via MFMA (bf16 hi/lo 3-pass) + BN + SiLU ----------------
__global__ void __launch_bounds__(256, 3) k_conv(const float* __restrict__ F, const float* __restrict__ W,
                                                 const float* __restrict__ gamma, const float* __restrict__ beta,
                                                 const float* __restrict__ mean, const float* __restrict__ var,
                                                 float* __restrict__ out) {
    __shared__ __align__(16) char lds[49408];   // Wh 8K | Wl 8K | Ff[64][129] fp32 33024B
    char* Wh = lds;
    char* Wl = lds + 8192;
    float* Ff = (float*)(lds + 16384);
    const int b = blockIdx.z;
    const int o0 = blockIdx.y * 64;
    const int p0 = blockIdx.x * 128;
    const int tid = threadIdx.x;
    const int l = tid & 63, wid = tid >> 6;
    const int wr = wid >> 1, wc = wid & 1;      // wave tile: 32 o x 64 p
    const int lr = l & 15, lk = l >> 4;
    const float* Wbase = W + (size_t)o0 * CC;
    const float* Fb = F + (size_t)b * CC * NA;

    f32x4 acc[2][4];
#pragma unroll
    for (int mf = 0; mf < 2; ++mf)
#pragma unroll
        for (int nf = 0; nf < 4; ++nf) acc[mf][nf] = (f32x4){0.f, 0.f, 0.f, 0.f};

    for (int kt = 0; kt < 4; ++kt) {
        __syncthreads();
        // stage W 64o x 64c -> swizzled bf16 hi/lo
#pragma unroll
        for (int rep = 0; rep < 2; ++rep) {
            int lin = rep * 256 + tid;
            int r = lin >> 3, g = lin & 7;
            const float* sp = Wbase + (size_t)r * CC + kt * 64 + g * 8;
            float4 q0 = *(const float4*)sp;
            float4 q1 = *(const float4*)(sp + 4);
            bf16x8 h8, l8;
            split8(q0, q1, h8, l8);
            int off = r * 128 + ((g ^ (r & 7)) << 4);
            *(bf16x8*)(Wh + off) = h8;
            *(bf16x8*)(Wl + off) = l8;
        }
        // stage F 64c x 128p fp32 (c-major, pad 129), coalesced loads
#pragma unroll
        for (int rep = 0; rep < 8; ++rep) {
            int lin = rep * 256 + tid;
            int c = lin >> 5, i4 = lin & 31;
            float4 fv = *(const float4*)(Fb + (size_t)(kt * 64 + c) * NA + p0 + i4 * 4);
            float* dp = Ff + c * 129 + i4 * 4;
            dp[0] = fv.x; dp[1] = fv.y; dp[2] = fv.z; dp[3] = fv.w;
        }
        __syncthreads();
#pragma unroll
        for (int ks = 0; ks < 2; ++ks) {
            bf16x8 whi[2], wlo[2];
#pragma unroll
            for (int mf = 0; mf < 2; ++mf) {
                int ra = wr * 32 + mf * 16 + lr;
                int offa = ra * 128 + (((ks * 4 + lk) ^ (ra & 7)) << 4);
                whi[mf] = *(const bf16x8*)(Wh + offa);
                wlo[mf] = *(const bf16x8*)(Wl + offa);
            }
#pragma unroll
            for (int nf = 0; nf < 4; ++nf) {
                int rb = wc * 64 + nf * 16 + lr;          // p within tile
                const float* cp = Ff + (ks * 4 + lk) * 8 * 129 + rb;
                bf16x8 bhi, blo;
#pragma unroll
                for (int e = 0; e < 8; ++e) {
                    float fv = cp[e * 129];
                    uint u = __float_as_uint(fv);
                    bhi[e] = (short)(u >> 16);
                    float hf = __uint_as_float(u & 0xffff0000u);
                    blo[e] = (short)(__float_as_uint(fv - hf) >> 16);
                }
#pragma unroll
                for (int mf = 0; mf < 2; ++mf) {
                    acc[mf][nf] = __builtin_amdgcn_mfma_f32_16x16x32_bf16(whi[mf], blo, acc[mf][nf], 0, 0, 0);
                    acc[mf][nf] = __builtin_amdgcn_mfma_f32_16x16x32_bf16(wlo[mf], bhi, acc[mf][nf], 0, 0, 0);
                    acc[mf][nf] = __builtin_amdgcn_mfma_f32_16x16x32_bf16(whi[mf], bhi, acc[mf][nf], 0, 0, 0);
                }
            }
        }
    }
    // epilogue: BN + SiLU; D row=o (lk*4+reg within 16), col=p (lr) [m89]
#pragma unroll
    for (int mf = 0; mf < 2; ++mf)
#pragma unroll
        for (int reg = 0; reg < 4; ++reg) {
            int o = o0 + wr * 32 + mf * 16 + lk * 4 + reg;
            float sc = gamma[o] / sqrtf(var[o] + 1e-5f);
            float sh = fmaf(-mean[o], sc, beta[o]);
#pragma unroll
            for (int nf = 0; nf < 4; ++nf) {
                float y = fmaf(acc[mf][nf][reg], sc, sh);
                out[((size_t)b * OC + o) * NA + p0 + wc * 64 + nf * 16 + lr] = y / (1.f + expf(-y));
            }
        }
}

extern "C" void kernel_launch(void* const* d_in, const int* in_sizes, int n_in,
                              void* d_out, int out_size, void* d_ws, size_t ws_size,
                              hipStream_t stream) {
    const float* x      = (const float*)d_in[0];
    const float* conv_w = (const float*)d_in[1];
    const float* gamma  = (const float*)d_in[2];
    const float* beta   = (const float*)d_in[3];
    const float* mean   = (const float*)d_in[4];
    const float* var    = (const float*)d_in[5];
    const float* fw     = (const float*)d_in[6];
    float* out = (float*)d_out;

    float* ws     = (float*)d_ws;
    float* norms4 = ws;                                      // 4*NTOK f
    float* Ap     = norms4 + (size_t)4 * NTOK;               // BB*NA*CC f
    float* Bp     = Ap + (size_t)BB * NA * CC;               // BB*NB*CC f
    float* Pv1    = Bp + (size_t)BB * NB * CC;               // BB*NPART*NA f
    float* Pv2    = Pv1 + (size_t)BB * NPART * NA;           // BB*NPART*NA f
    int*   Pi1    = (int*)(Pv2 + (size_t)BB * NPART * NA);   // BB*NPART*NA i
    int*   sel    = Pi1 + (size_t)BB * NPART * NA;           // BB*NA i
    int*   wl     = sel + (size_t)BB * NA;                   // BB*NA i
    int*   count  = wl + (size_t)BB * NA;                    // 1 i
    float* F      = Ap;                                      // reuse Ap region after fallback

    k_norm<<<NTOK / 256, 256, 0, stream>>>(x, norms4, count);
    k_pack<<<dim3(TT / 64, CC / 64, BB), 256, 0, stream>>>(x, norms4, Ap, Bp);
    k_sim<<<8 * NCH * BB, 256, 0, stream>>>(Ap, Bp, Pv1, Pi1, Pv2);
    k_reduce2<<<BB * NA / 256, 256, 0, stream>>>(Pv1, Pi1, Pv2, sel, wl, count);
    k_fallback<<<2048, 512, 0, stream>>>(Ap, Bp, wl, count, sel);
    k_fuse<<<dim3(CC, BB), 256, 0, stream>>>(x, sel, fw, F);
    k_conv<<<dim3(NA / 128, OC / 64, BB), 256, 0, stream>>>(F, conv_w, gamma, beta, mean, var, out);
}

// Round 22
// 252.813 us; speedup vs baseline: 1.2806x; 1.0270x over previous
//
#include <hip/hip_runtime.h>
#include <math.h>

#define BB 16
#define CC 256
#define TT 4096
#define NA 1024
#define NB 3072
#define OC 512

#define NCH 12         // j-chunks for MFMA sim kernel (256 j each = 2 tiles of 128)
#define NPART (NCH*2)  // partials: chunk x wc-half (race-free direct per-wave writes)
#define DELTA 2e-4f    // margin below which a row falls back to exact fp32 argmax

typedef float f32x4 __attribute__((ext_vector_type(4)));
typedef short bf16x8 __attribute__((ext_vector_type(8)));

// ---------------- K2: fused norm + transpose-pack (x read ONCE) ----------------
// One block per (t-tile of 64 tokens, batch): stage all 256 c in LDS (64x260 pad),
// accumulate sum-of-squares partials during the coalesced load, reduce -> ns[t],
// then per-token float4 LDS reads / ns with 1KB-contiguous global writes.
__global__ void __launch_bounds__(256, 2) k_pack(const float* __restrict__ x,
                                                 float* __restrict__ Ap, float* __restrict__ Bp,
                                                 int* __restrict__ count) {
    __shared__ float tilT[64][260];   // [token][c], pad 260 (mult of 4: aligned float4 rows)
    __shared__ float psum[64][17];    // [token][c-group]
    __shared__ float ns[64];
    int b = blockIdx.y, t0 = blockIdx.x * 64;
    int tid = threadIdx.x;
    if (tid == 0 && blockIdx.x == 0 && b == 0) *count = 0;
    int hi = tid >> 4, j4 = tid & 15;           // c-group lane, token-quad
    float ps0 = 0.f, ps1 = 0.f, ps2 = 0.f, ps3 = 0.f;
#pragma unroll
    for (int rep = 0; rep < 16; ++rep) {
        int i = rep * 16 + hi;                  // c row
        float4 v = *(const float4*)(x + ((size_t)b * CC + i) * TT + t0 + j4 * 4);
        tilT[j4 * 4 + 0][i] = v.x;
        tilT[j4 * 4 + 1][i] = v.y;
        tilT[j4 * 4 + 2][i] = v.z;
        tilT[j4 * 4 + 3][i] = v.w;
        ps0 = fmaf(v.x, v.x, ps0);
        ps1 = fmaf(v.y, v.y, ps1);
        ps2 = fmaf(v.z, v.z, ps2);
        ps3 = fmaf(v.w, v.w, ps3);
    }
    psum[j4 * 4 + 0][hi] = ps0;
    psum[j4 * 4 + 1][hi] = ps1;
    psum[j4 * 4 + 2][hi] = ps2;
    psum[j4 * 4 + 3][hi] = ps3;
    __syncthreads();
    if (tid < 64) {
        float s = 0.f;
#pragma unroll
        for (int g = 0; g < 16; ++g) s += psum[tid][g];
        ns[tid] = sqrtf(s);
    }
    __syncthreads();
#pragma unroll
    for (int rep = 0; rep < 16; ++rep) {
        int lin = rep * 256 + tid;
        int j = lin >> 6, i4 = lin & 63;        // token, c-quad
        float nsj = ns[j];
        const float* rp = &tilT[j][i4 * 4];
        float4 o;
        o.x = rp[0] / nsj;
        o.y = rp[1] / nsj;
        o.z = rp[2] / nsj;
        o.w = rp[3] / nsj;
        int t = t0 + j;
        if ((t & 3) == 0) {
            *(float4*)(Ap + ((size_t)b * NA + (t >> 2)) * CC + i4 * 4) = o;
        } else {
            int g = t >> 2, r = t & 3;
            *(float4*)(Bp + ((size_t)b * NB + 3 * g + (r - 1)) * CC + i4 * 4) = o;
        }
    }
}

// ---------------- K3: MFMA sim; T14 async-STAGE + T1 XCD-aware block swizzle ----------------
__device__ inline void split8(float4 p0, float4 p1, bf16x8& hi, bf16x8& lo) {
    float f[8] = {p0.x, p0.y, p0.z, p0.w, p1.x, p1.y, p1.z, p1.w};
#pragma unroll
    for (int j = 0; j < 8; ++j) {
        uint u = __float_as_uint(f[j]);
        hi[j] = (short)(u >> 16);
        float hf = __uint_as_float(u & 0xffff0000u);
        lo[j] = (short)(__float_as_uint(f[j] - hf) >> 16);
    }
}

#define LOADT(SRC_BASE, KT, RG)                                                   \
    _Pragma("unroll")                                                             \
    for (int rep = 0; rep < 4; ++rep) {                                           \
        int lin = rep * 256 + tid;                                                \
        int r = lin >> 3, g = lin & 7;                                            \
        const float* sp = (SRC_BASE) + (size_t)r * CC + (KT) * 64 + g * 8;        \
        RG[rep][0] = *(const float4*)sp;                                          \
        RG[rep][1] = *(const float4*)(sp + 4);                                    \
    }

#define WRITET(RG, DH, DL)                                                        \
    _Pragma("unroll")                                                             \
    for (int rep = 0; rep < 4; ++rep) {                                           \
        int lin = rep * 256 + tid;                                                \
        int r = lin >> 3, g = lin & 7;                                            \
        bf16x8 h8, l8;                                                            \
        split8(RG[rep][0], RG[rep][1], h8, l8);                                   \
        int off = r * 128 + ((g ^ (r & 7)) << 4);                                 \
        *(bf16x8*)((DH) + off) = h8;                                              \
        *(bf16x8*)((DL) + off) = l8;                                              \
    }

#define MFMA_TILE(ACC)                                                            \
    _Pragma("unroll")                                                             \
    for (int ks = 0; ks < 2; ++ks) {                                              \
        bf16x8 ahi[4], alo[4];                                                    \
        _Pragma("unroll")                                                         \
        for (int mf = 0; mf < 4; ++mf) {                                          \
            int ra = wr * 64 + mf * 16 + lr;                                      \
            int offa = ra * 128 + (((ks * 4 + lk) ^ (ra & 7)) << 4);              \
            ahi[mf] = *(const bf16x8*)(Ah + offa);                                \
            alo[mf] = *(const bf16x8*)(Al + offa);                                \
        }                                                                         \
        _Pragma("unroll")                                                         \
        for (int nf = 0; nf < 4; ++nf) {                                          \
            int rb = wc * 64 + nf * 16 + lr;                                      \
            int offb = rb * 128 + (((ks * 4 + lk) ^ (rb & 7)) << 4);              \
            bf16x8 bhi = *(const bf16x8*)(Bh + offb);                             \
            bf16x8 blo = *(const bf16x8*)(Bl + offb);                             \
            _Pragma("unroll")                                                     \
            for (int mf = 0; mf < 4; ++mf) {                                      \
                ACC[mf][nf] = __builtin_amdgcn_mfma_f32_16x16x32_bf16(ahi[mf], blo, ACC[mf][nf], 0, 0, 0); \
                ACC[mf][nf] = __builtin_amdgcn_mfma_f32_16x16x32_bf16(alo[mf], bhi, ACC[mf][nf], 0, 0, 0); \
                ACC[mf][nf] = __builtin_amdgcn_mfma_f32_16x16x32_bf16(ahi[mf], bhi, ACC[mf][nf], 0, 0, 0); \
            }                                                                     \
        }                                                                         \
    }

// per-row top2 over one 128-col tile; D mapping col=lane&15, row=(lane>>4)*4+reg [m89]
#define TOP2(ACC, JBASE)                                                          \
    _Pragma("unroll")                                                             \
    for (int mf = 0; mf < 4; ++mf)                                                \
    _Pragma("unroll")                                                             \
        for (int reg = 0; reg < 4; ++reg) {                                       \
            int q = mf * 4 + reg;                                                 \
            float v1 = ACC[mf][0][reg];                                           \
            int i1 = (JBASE) + wc * 64 + lr;                                      \
            float v2 = -1e30f;                                                    \
            _Pragma("unroll")                                                     \
            for (int nf = 1; nf < 4; ++nf) {                                      \
                float xv = ACC[mf][nf][reg];                                      \
                int xi = (JBASE) + wc * 64 + nf * 16 + lr;                        \
                if (xv > v1) { v2 = v1; v1 = xv; i1 = xi; }                       \
                else v2 = fmaxf(v2, xv);                                          \
            }                                                                     \
            _Pragma("unroll")                                                     \
            for (int d = 1; d < 16; d <<= 1) {                                    \
                float ov1 = __shfl_xor(v1, d, 64);                                \
                int oi1 = __shfl_xor(i1, d, 64);                                  \
                float ov2 = __shfl_xor(v2, d, 64);                                \
                bool take = (ov1 > v1) || (ov1 == v1 && oi1 < i1);                \
                float bw = take ? v1 : ov1;                                       \
                v2 = fmaxf(fmaxf(v2, ov2), bw);                                   \
                if (take) { v1 = ov1; i1 = oi1; }                                 \
            }                                                                     \
            bool t2 = (v1 > rv1[q]);                                              \
            float bw2 = t2 ? rv1[q] : v1;                                         \
            rv2[q] = fmaxf(fmaxf(rv2[q], v2), bw2);                               \
            if (t2) { rv1[q] = v1; ri1[q] = i1; }                                 \
        }

__global__ void __launch_bounds__(256, 2) k_sim(const float* __restrict__ Ap,
                                                const float* __restrict__ Bp,
                                                float* __restrict__ Pv1, int* __restrict__ Pi1,
                                                float* __restrict__ Pv2) {
    __shared__ __align__(16) char lds[65536];   // Ah|Al|Bh|Bl, 16KB each ([128][64] bf16 swizzled)
    char* Ah = lds;
    char* Al = lds + 16384;
    char* Bh = lds + 32768;
    char* Bl = lds + 49152;
    // T1: XCD-aware bijective swizzle of the 1536-block 1D grid (1536 % 8 == 0).
    const int flat = blockIdx.x;
    const int swz = (flat & 7) * 192 + (flat >> 3);
    const int bx = swz & 7;                     // i-tile (8)
    const int rest = swz >> 3;
    const int ch = rest % NCH;                  // j-chunk (12)
    const int b = rest / NCH;                   // batch (16)
    const int i0 = bx * 128;
    const int tid = threadIdx.x;
    const int l = tid & 63, wid = tid >> 6;
    const int wr = wid >> 1, wc = wid & 1;      // 2x2 wave grid, 64x64 per wave per tile
    const int lr = l & 15, lk = l >> 4;
    const float* Abase = Ap + ((size_t)b * NA + i0) * CC;
    const float* Bbase = Bp + (size_t)b * NB * CC;
    const int j0c = ch * 256;

    float rv1[16], rv2[16];
    int ri1[16];
#pragma unroll
    for (int q = 0; q < 16; ++q) { rv1[q] = -1e30f; rv2[q] = -1e30f; ri1[q] = 0; }

    f32x4 acc0[4][4], acc1[4][4];
#pragma unroll
    for (int mf = 0; mf < 4; ++mf)
#pragma unroll
        for (int nf = 0; nf < 4; ++nf) {
            acc0[mf][nf] = (f32x4){0.f, 0.f, 0.f, 0.f};
            acc1[mf][nf] = (f32x4){0.f, 0.f, 0.f, 0.f};
        }

    float4 rA[4][2], rB[4][2];
    LOADT(Abase, 0, rA)
    LOADT(Bbase + (size_t)j0c * CC, 0, rB)

    for (int kt = 0; kt < 4; ++kt) {
        __syncthreads();                      // prior tile reads done
        WRITET(rA, Ah, Al)                    // split+write prefetched A,B1
        WRITET(rB, Bh, Bl)
        __syncthreads();
        LOADT(Bbase + (size_t)(j0c + 128) * CC, kt, rB)   // issue B2 loads under MFMA0
        MFMA_TILE(acc0)
        __syncthreads();                      // MFMA0 done reading Bh/Bl
        WRITET(rB, Bh, Bl)
        __syncthreads();
        if (kt < 3) {                         // issue next-kt A,B1 loads under MFMA1
            LOADT(Abase, kt + 1, rA)
            LOADT(Bbase + (size_t)j0c * CC, kt + 1, rB)
        }
        MFMA_TILE(acc1)
    }

    TOP2(acc0, j0c)                           // ascending j: tile0 then tile1
    TOP2(acc1, j0c + 128)

    // race-free: each wave writes its own (chunk, wc-half) partial
    if (lr == 0) {
        int pch = ch * 2 + wc;
#pragma unroll
        for (int mf = 0; mf < 4; ++mf)
#pragma unroll
            for (int reg = 0; reg < 4; ++reg) {
                int row = i0 + wr * 64 + mf * 16 + lk * 4 + reg;
                size_t o = ((size_t)b * NPART + pch) * NA + row;
                int q = mf * 4 + reg;
                Pv1[o] = rv1[q]; Pi1[o] = ri1[q]; Pv2[o] = rv2[q];
            }
    }
}

// ---------------- K3b: merge partials -> sel + compact flagged worklist ----------------
__global__ void k_reduce2(const float* __restrict__ Pv1, const int* __restrict__ Pi1,
                          const float* __restrict__ Pv2, int* __restrict__ sel,
                          int* __restrict__ wl, int* __restrict__ count) {
    int idx = blockIdx.x * 256 + threadIdx.x;   // b*NA + a
    int b = idx >> 10;
    int a = idx & 1023;
    float v1 = -1e30f, v2 = -1e30f;
    int i1 = 0x7fffffff;
#pragma unroll
    for (int pc = 0; pc < NPART; ++pc) {
        size_t o = ((size_t)b * NPART + pc) * NA + a;
        float nv1 = Pv1[o];
        int ni1 = Pi1[o];
        bool take = (nv1 > v1) || (nv1 == v1 && ni1 < i1);
        float bw = take ? v1 : nv1;
        v2 = fmaxf(fmaxf(v2, Pv2[o]), bw);
        if (take) { v1 = nv1; i1 = ni1; }
    }
    int g = i1 / 3, r = i1 - 3 * g;
    sel[idx] = 4 * g + r + 1;
    if (v1 - v2 < DELTA) {
        int p = atomicAdd(count, 1);
        wl[p] = idx;
    }
}

// ---------------- K3c: exact fp32 re-argmax for flagged rows (worklist) ----------------
__global__ void __launch_bounds__(512) k_fallback(const float* __restrict__ Ap,
                                                  const float* __restrict__ Bp,
                                                  const int* __restrict__ wl,
                                                  const int* __restrict__ count,
                                                  int* __restrict__ sel) {
    int n = *count;
    __shared__ float arow[CC];
    __shared__ float wv[8];
    __shared__ int wi[8];
    int tid = threadIdx.x;                // 512 threads = 8 waves
    int l = tid & 63, w = tid >> 6;
    int lg = l & 15, grp = l >> 4;
    for (int it = blockIdx.x; it < n; it += gridDim.x) {
        int row = wl[it];
        int b = row >> 10, a = row & 1023;
        __syncthreads();                  // protect arow/wv reuse across iterations
        if (tid < 64) *(float4*)&arow[tid * 4] = *(const float4*)(Ap + ((size_t)b * NA + a) * CC + tid * 4);
        __syncthreads();
        float4 av[4];
#pragma unroll
        for (int q = 0; q < 4; ++q) av[q] = *(const float4*)&arow[q * 64 + lg * 4];
        const float* Bb = Bp + (size_t)b * NB * CC;
        float bv = -1e30f;
        int bi = 0;
        for (int j = w * 4 + grp; j < NB; j += 32) {
            const float* br = Bb + (size_t)j * CC + lg * 4;
            float s = 0.f;
#pragma unroll
            for (int q = 0; q < 4; ++q) {
                float4 bb = *(const float4*)(br + q * 64);
                s = fmaf(av[q].w, bb.w, fmaf(av[q].z, bb.z, fmaf(av[q].y, bb.y, fmaf(av[q].x, bb.x, s))));
            }
#pragma unroll
            for (int d = 1; d < 16; d <<= 1) s += __shfl_xor(s, d, 64);
            if (lg == 0 && s > bv) { bv = s; bi = j; }   // ascending per group-lead
        }
#pragma unroll
        for (int d = 16; d < 64; d <<= 1) {
            float ov = __shfl_xor(bv, d, 64);
            int oi = __shfl_xor(bi, d, 64);
            if (ov > bv || (ov == bv && oi < bi)) { bv = ov; bi = oi; }
        }
        if (l == 0) { wv[w] = bv; wi[w] = bi; }
        __syncthreads();
        if (tid == 0) {
            float vm = wv[0]; int im = wi[0];
#pragma unroll
            for (int q = 1; q < 8; ++q)
                if (wv[q] > vm || (wv[q] == vm && wi[q] < im)) { vm = wv[q]; im = wi[q]; }
            int g = im / 3, r = im - 3 * g;
            sel[row] = 4 * g + r + 1;
        }
    }
}

// ---------------- K4a: fuse; one block per (b,c), x-row staged in LDS ----------------
__global__ void k_fuse(const float* __restrict__ x, const int* __restrict__ sel,
                       const float* __restrict__ fwraw, float* __restrict__ F) {
    __shared__ float row[TT];
    int b = blockIdx.y, c = blockIdx.x;
    int tid = threadIdx.x;
    const float* xr = x + ((size_t)b * CC + c) * TT;
#pragma unroll
    for (int r = 0; r < 4; ++r)
        *(float4*)&row[r * 1024 + tid * 4] = *(const float4*)(xr + r * 1024 + tid * 4);
    float w0 = fminf(fmaxf(fwraw[0], 0.f), 6.f);
    float w1 = fminf(fmaxf(fwraw[1], 0.f), 6.f);
    float s = w0 + w1 + 1e-8f;
    float fw0 = w0 / s, fw1 = w1 / s;
    __syncthreads();
    float4 outv;
    float* op = &outv.x;
#pragma unroll
    for (int u = 0; u < 4; ++u) {
        int p = tid * 4 + u;
        int lin = 4 * p;
        int spa = ((lin & 63) == 0) ? lin + 1 : lin - 1;
        int ssim = sel[b * NA + p];
        float xa = row[lin], xs = row[ssim], xp = row[spa];
        float ms = (xa + xs) * 0.5f;
        float mp = (xa + xp) * 0.5f;
        op[u] = fw0 * ms + fw1 * mp;
    }
    *(float4*)(F + ((size_t)b * CC + c) * NA + tid * 4) = outv;
}

// ---------------- K4b: 1x1 conv via MFMA (bf16 hi/lo 3-pass) + BN + SiLU ----------------
__global__ void __launch_bounds__(256, 3) k_conv(const float* __restrict__ F, const float* __restrict__ W,
                                                 const float* __restrict__ gamma, const float* __restrict__ beta,
                                                 const float* __restrict__ mean, const float* __restrict__ var,
                                                 float* __restrict__ out) {
    __shared__ __align__(16) char lds[49408];   // Wh 8K | Wl 8K | Ff[64][129] fp32 33024B
    char* Wh = lds;
    char* Wl = lds + 8192;
    float* Ff = (float*)(lds + 16384);
    const int b = blockIdx.z;
    const int o0 = blockIdx.y * 64;
    const int p0 = blockIdx.x * 128;
    const int tid = threadIdx.x;
    const int l = tid & 63, wid = tid >> 6;
    const int wr = wid >> 1, wc = wid & 1;      // wave tile: 32 o x 64 p
    const int lr = l & 15, lk = l >> 4;
    const float* Wbase = W + (size_t)o0 * CC;
    const float* Fb = F + (size_t)b * CC * NA;

    f32x4 acc[2][4];
#pragma unroll
    for (int mf = 0; mf < 2; ++mf)
#pragma unroll
        for (int nf = 0; nf < 4; ++nf) acc[mf][nf] = (f32x4){0.f, 0.f, 0.f, 0.f};

    for (int kt = 0; kt < 4; ++kt) {
        __syncthreads();
        // stage W 64o x 64c -> swizzled bf16 hi/lo
#pragma unroll
        for (int rep = 0; rep < 2; ++rep) {
            int lin = rep * 256 + tid;
            int r = lin >> 3, g = lin & 7;
            const float* sp = Wbase + (size_t)r * CC + kt * 64 + g * 8;
            float4 q0 = *(const float4*)sp;
            float4 q1 = *(const float4*)(sp + 4);
            bf16x8 h8, l8;
            split8(q0, q1, h8, l8);
            int off = r * 128 + ((g ^ (r & 7)) << 4);
            *(bf16x8*)(Wh + off) = h8;
            *(bf16x8*)(Wl + off) = l8;
        }
        // stage F 64c x 128p fp32 (c-major, pad 129), coalesced loads
#pragma unroll
        for (int rep = 0; rep < 8; ++rep) {
            int lin = rep * 256 + tid;
            int c = lin >> 5, i4 = lin & 31;
            float4 fv = *(const float4*)(Fb + (size_t)(kt * 64 + c) * NA + p0 + i4 * 4);
            float* dp = Ff + c * 129 + i4 * 4;
            dp[0] = fv.x; dp[1] = fv.y; dp[2] = fv.z; dp[3] = fv.w;
        }
        __syncthreads();
#pragma unroll
        for (int ks = 0; ks < 2; ++ks) {
            bf16x8 whi[2], wlo[2];
#pragma unroll
            for (int mf = 0; mf < 2; ++mf) {
                int ra = wr * 32 + mf * 16 + lr;
                int offa = ra * 128 + (((ks * 4 + lk) ^ (ra & 7)) << 4);
                whi[mf] = *(const bf16x8*)(Wh + offa);
                wlo[mf] = *(const bf16x8*)(Wl + offa);
            }
#pragma unroll
            for (int nf = 0; nf < 4; ++nf) {
                int rb = wc * 64 + nf * 16 + lr;          // p within tile
                const float* cp = Ff + (ks * 4 + lk) * 8 * 129 + rb;
                bf16x8 bhi, blo;
#pragma unroll
                for (int e = 0; e < 8; ++e) {
                    float fv = cp[e * 129];
                    uint u = __float_as_uint(fv);
                    bhi[e] = (short)(u >> 16);
                    float hf = __uint_as_float(u & 0xffff0000u);
                    blo[e] = (short)(__float_as_uint(fv - hf) >> 16);
                }
#pragma unroll
                for (int mf = 0; mf < 2; ++mf) {
                    acc[mf][nf] = __builtin_amdgcn_mfma_f32_16x16x32_bf16(whi[mf], blo, acc[mf][nf], 0, 0, 0);
                    acc[mf][nf] = __builtin_amdgcn_mfma_f32_16x16x32_bf16(wlo[mf], bhi, acc[mf][nf], 0, 0, 0);
                    acc[mf][nf] = __builtin_amdgcn_mfma_f32_16x16x32_bf16(whi[mf], bhi, acc[mf][nf], 0, 0, 0);
                }
            }
        }
    }
    // epilogue: BN + SiLU; D row=o (lk*4+reg within 16), col=p (lr) [m89]
#pragma unroll
    for (int mf = 0; mf < 2; ++mf)
#pragma unroll
        for (int reg = 0; reg < 4; ++reg) {
            int o = o0 + wr * 32 + mf * 16 + lk * 4 + reg;
            float sc = gamma[o] / sqrtf(var[o] + 1e-5f);
            float sh = fmaf(-mean[o], sc, beta[o]);
#pragma unroll
            for (int nf = 0; nf < 4; ++nf) {
                float y = fmaf(acc[mf][nf][reg], sc, sh);
                out[((size_t)b * OC + o) * NA + p0 + wc * 64 + nf * 16 + lr] = y / (1.f + expf(-y));
            }
        }
}

extern "C" void kernel_launch(void* const* d_in, const int* in_sizes, int n_in,
                              void* d_out, int out_size, void* d_ws, size_t ws_size,
                              hipStream_t stream) {
    const float* x      = (const float*)d_in[0];
    const float* conv_w = (const float*)d_in[1];
    const float* gamma  = (const float*)d_in[2];
    const float* beta   = (const float*)d_in[3];
    const float* mean   = (const float*)d_in[4];
    const float* var    = (const float*)d_in[5];
    const float* fw     = (const float*)d_in[6];
    float* out = (float*)d_out;

    float* ws     = (float*)d_ws;
    float* Ap     = ws;                                      // BB*NA*CC f
    float* Bp     = Ap + (size_t)BB * NA * CC;               // BB*NB*CC f
    float* Pv1    = Bp + (size_t)BB * NB * CC;               // BB*NPART*NA f
    float* Pv2    = Pv1 + (size_t)BB * NPART * NA;           // BB*NPART*NA f
    int*   Pi1    = (int*)(Pv2 + (size_t)BB * NPART * NA);   // BB*NPART*NA i
    int*   sel    = Pi1 + (size_t)BB * NPART * NA;           // BB*NA i
    int*   wl     = sel + (size_t)BB * NA;                   // BB*NA i
    int*   count  = wl + (size_t)BB * NA;                    // 1 i
    float* F      = Ap;                                      // reuse Ap region after fallback

    k_pack<<<dim3(TT / 64, BB), 256, 0, stream>>>(x, Ap, Bp, count);
    k_sim<<<8 * NCH * BB, 256, 0, stream>>>(Ap, Bp, Pv1, Pi1, Pv2);
    k_reduce2<<<BB * NA / 256, 256, 0, stream>>>(Pv1, Pi1, Pv2, sel, wl, count);
    k_fallback<<<2048, 512, 0, stream>>>(Ap, Bp, wl, count, sel);
    k_fuse<<<dim3(CC, BB), 256, 0, stream>>>(x, sel, fw, F);
    k_conv<<<dim3(NA / 128, OC / 64, BB), 256, 0, stream>>>(F, conv_w, gamma, beta, mean, var, out);
}